// Round 1
// 555.024 us; speedup vs baseline: 1.0542x; 1.0542x over previous
//
#include <hip/hip_runtime.h>

typedef unsigned short u16;
typedef __attribute__((ext_vector_type(8))) __bf16 bf16x8;
typedef __attribute__((ext_vector_type(4))) float floatx4;

#define B_DIM  16
#define S_DIM  2048
#define E_DIM  768
#define HEADS  8
#define DHEAD  96
#define MROWS  32768    // B_DIM * S_DIM
#define QKV_LD 2304     // 3*E_DIM
#define ATT_ST 392      // attn LDS row stride in u16
#define NT     12       // K tiles of 64 (K=768)

#define GLDS(gp, lp) __builtin_amdgcn_global_load_lds( \
    (const __attribute__((address_space(1))) void*)(gp), \
    (__attribute__((address_space(3))) void*)(lp), 16, 0, 0)

__device__ __forceinline__ u16 f2b(float f) {
    unsigned u = __float_as_uint(f);
    u += 0x7fffu + ((u >> 16) & 1u);   // RNE
    return (u16)(u >> 16);
}
__device__ __forceinline__ float blo(unsigned u) { return __uint_as_float(u << 16); }
__device__ __forceinline__ float bhi(unsigned u) { return __uint_as_float(u & 0xffff0000u); }

__device__ __forceinline__ void axpy8(float* acc, float p, uint4 v) {
    acc[0] += p * blo(v.x); acc[1] += p * bhi(v.x);
    acc[2] += p * blo(v.y); acc[3] += p * bhi(v.y);
    acc[4] += p * blo(v.z); acc[5] += p * bhi(v.z);
    acc[6] += p * blo(v.w); acc[7] += p * bhi(v.w);
}

// swizzled LDS fragment read: half_base is a [128][64] bf16 half-tile,
// physical chunk layout LDS[r][q] holds logical (r, q^(r&7))  (see staging)
__device__ __forceinline__ bf16x8 ldsw(const u16* half_base, int rowh, int cb) {
    return *(const bf16x8*)((const char*)half_base + rowh * 128 + (cb ^ ((rowh & 7) << 4)));
}

// ---------------- merged prep: cvt fbf / wib / w1b, transpose WoT, cbias ----------------
#define PB0 24576   // fbf cvt blocks   (32768*768/4/256)
#define PB1 26304   // + wib 1728       (2304*768/4/256)
#define PB2 26592   // + w1b 288        (384*768/4/256)
#define PB3 27168   // + transpose 576  (24*24)
#define PB4 27552   // + cbias 384
__global__ __launch_bounds__(256) void prep(const float* __restrict__ features,
                                            const float* __restrict__ in_proj_w,
                                            const float* __restrict__ w1,
                                            const float* __restrict__ out_proj_w,
                                            const float* __restrict__ bo,
                                            const float* __restrict__ b1,
                                            u16* __restrict__ fbf, u16* __restrict__ wib,
                                            u16* __restrict__ w1b, u16* __restrict__ WoT,
                                            float* __restrict__ cbuf) {
    __shared__ float tsh[32][33];
    const int b = blockIdx.x, tid = threadIdx.x;
    if (b < PB2) {   // the three fp32->bf16 copies
        const float* src; u16* dst; long i;
        if (b < PB0)      { src = features;  dst = fbf; i = (long)b * 256 + tid; }
        else if (b < PB1) { src = in_proj_w; dst = wib; i = (long)(b - PB0) * 256 + tid; }
        else              { src = w1;        dst = w1b; i = (long)(b - PB1) * 256 + tid; }
        float4 f = ((const float4*)src)[i];
        ushort4 r;
        r.x = f2b(f.x); r.y = f2b(f.y); r.z = f2b(f.z); r.w = f2b(f.w);
        ((ushort4*)dst)[i] = r;
    } else if (b < PB3) {   // 768x768 transpose+cvt of out_proj_w
        const int t = b - PB2;
        const int bxT = t % 24, byT = t / 24;
        const int tx = tid & 31, ty = tid >> 5;
        int x = bxT * 32 + tx;
        int y = byT * 32 + ty;
#pragma unroll
        for (int j = 0; j < 4; j++) tsh[ty + j * 8][tx] = out_proj_w[(long)(y + j * 8) * 768 + x];
        __syncthreads();
        x = byT * 32 + tx;
        y = bxT * 32 + ty;
#pragma unroll
        for (int j = 0; j < 4; j++) WoT[(long)(y + j * 8) * 768 + x] = f2b(tsh[tx][ty + j * 8]);
    } else {   // cbias: c[n] = b1[n] + W1[n,:]·bo
        const int n = b - PB3;
        const float* row = w1 + (long)n * 768;
        float s = row[tid] * bo[tid] + row[tid + 256] * bo[tid + 256] + row[tid + 512] * bo[tid + 512];
#pragma unroll
        for (int off = 32; off > 0; off >>= 1) s += __shfl_xor(s, off);
        if ((tid & 63) == 0) tsh[0][tid >> 6] = s;
        __syncthreads();
        if (tid == 0) cbuf[n] = tsh[0][0] + tsh[0][1] + tsh[0][2] + tsh[0][3] + b1[n];
    }
}

// ---------------- QKV (+G) GEMM: 256x256 tile, BK=64, 8-phase counted-vmcnt schedule ----------------
// Blocks [0,1152): qkv = features @ in_proj_w^T + b, s-major perm, XCD swizzle bm&7==xcd
//                  (so all rows of a given s, i.e. s>>8 group, are written by one XCD).
// Blocks [1152,1158): G = W1 @ Wo (M=384: second M-tile partial, stores guarded).
// Schedule (scheme T ledger, per thread 8 loads/tile):
//   boundary entering tile u: issue A-halves of u+1 (4 loads, buf freed by u-1's last
//   barrier), s_waitcnt vmcnt(4) -> everything older (all of tile u) landed, s_barrier.
//   P1 issues B0(u+1), P2 issues B1(u+1). A gets ~4-phase HBM cover; B is L2-resident.
//   Each phase: ds_read frags -> barrier -> lgkmcnt(0)+sched_barrier -> setprio(1),
//   16 MFMA, setprio(0) -> barrier.
// LDS swizzle: chunk q of row r stored from global chunk q^(r&7); reads XOR the byte
// addr with (r&7)<<4 -> 8 lanes per 4-bank group = conflict-free ds_read_b128.
__global__ __launch_bounds__(512, 2) void qkv256(const u16* __restrict__ A,
                                                 const u16* __restrict__ W,
                                                 const float* __restrict__ bias,
                                                 u16* __restrict__ Cout,
                                                 const u16* __restrict__ gA,
                                                 const u16* __restrict__ gW,
                                                 u16* __restrict__ gC) {
    __shared__ __align__(16) u16 lds[2 * 32768];   // 128 KiB: [p]{A:2x[128][64], B:2x[128][64]}
    const int tid = threadIdx.x;
    const int bx  = blockIdx.x;
    int bm, bn, ldc, Mvalid; const u16 *Aa, *Ww; const float* bs; u16* Co; bool perm;
    if (bx < 1152) {
        const int xcd = bx & 7;
        const int q   = bx >> 3;          // 0..143: 16 bm-groups x 9 bn (A-panel reuse per XCD)
        bn = q % 9;
        bm = (q / 9) * 8 + xcd;           // bm&7 == xcd
        Aa = A; Ww = W; bs = bias; Co = Cout; ldc = QKV_LD; perm = true; Mvalid = 1 << 30;
    } else {
        const int g = bx - 1152;
        bn = g % 3; bm = g / 3;           // M tiles: 2 (rows 256..511 partial), N tiles: 3
        Aa = gA; Ww = gW; bs = nullptr; Co = gC; ldc = 768; perm = false; Mvalid = 384;
    }
    // staging: chunk ci = ld*512+tid -> (row=ci>>3, q=ci&7); src chunk pre-swizzled q^(row&7)
    const int r0 = tid >> 3,        r1 = (tid + 512) >> 3;
    const int q0 = (tid & 7) ^ (r0 & 7), q1 = ((tid + 512) & 7) ^ (r1 & 7);
    const u16* pA0 = Aa + (long)(bm * 256 + r0) * 768 + q0 * 8;
    const u16* pA1 = Aa + (long)(bm * 256 + r1) * 768 + q1 * 8;
    const u16* pB0 = Ww + (long)(bn * 256 + r0) * 768 + q0 * 8;
    const u16* pB1 = Ww + (long)(bn * 256 + r1) * 768 + q1 * 8;
    u16* dA0 = lds + tid * 8;           // ld0 chunks  (+p*32768 +h*8192)
    u16* dA1 = lds + 4096 + tid * 8;    // ld1 chunks
    u16* dB0 = lds + 16384 + tid * 8;
    u16* dB1 = lds + 16384 + 4096 + tid * 8;

#define IS_A(h, p, t) do { \
    GLDS(pA0 + (h) * 98304 + (t) * 64, dA0 + (p) * 32768 + (h) * 8192); \
    GLDS(pA1 + (h) * 98304 + (t) * 64, dA1 + (p) * 32768 + (h) * 8192); } while (0)
#define IS_B(h, p, t) do { \
    GLDS(pB0 + (h) * 98304 + (t) * 64, dB0 + (p) * 32768 + (h) * 8192); \
    GLDS(pB1 + (h) * 98304 + (t) * 64, dB1 + (p) * 32768 + (h) * 8192); } while (0)
#define MFMA_PRE() do { \
    __builtin_amdgcn_s_barrier(); \
    asm volatile("s_waitcnt lgkmcnt(0)" ::: "memory"); \
    __builtin_amdgcn_sched_barrier(0); \
    __builtin_amdgcn_s_setprio(1); } while (0)
#define MFMA_POST() do { \
    __builtin_amdgcn_s_setprio(0); \
    __builtin_amdgcn_s_barrier(); } while (0)

    const int lane = tid & 63, wid = tid >> 6;
    const int wr = wid >> 2, wc = wid & 3;          // 2M x 4N waves, 128x64 per wave
    const int fr = lane & 15, fg = lane >> 4;
    const int fq2 = fg * 16;                        // ks0 col byte
    const int wb  = (wc & 1) * 64;                  // B row base within half
    const u16* bufA_base = lds + wr * 8192;
    const u16* bufB_base = lds + 16384 + (wc >> 1) * 8192;

    // prologue: tile0 complete + tile1 A-halves in flight
    IS_A(0, 0, 0); IS_A(1, 0, 0); IS_B(0, 0, 0); IS_B(1, 0, 0);
    IS_A(0, 1, 1); IS_A(1, 1, 1);
    asm volatile("s_waitcnt vmcnt(4)" ::: "memory");
    __builtin_amdgcn_s_barrier();

    floatx4 acc[8][4] = {};
#pragma unroll 2
    for (int t = 0; t < NT; ++t) {
        const int p = t & 1, pn = p ^ 1;
        const u16* bA = bufA_base + p * 32768;
        const u16* bB = bufB_base + p * 32768;
        bf16x8 aF[4], bF[4];
        // ---- P1: ks0, i 0-3 ----
#pragma unroll
        for (int i = 0; i < 4; ++i) aF[i] = ldsw(bA, i * 16 + fr, fq2);
#pragma unroll
        for (int j = 0; j < 4; ++j) bF[j] = ldsw(bB, wb + j * 16 + fr, fq2);
        if (t + 1 < NT) IS_B(0, pn, t + 1);
        MFMA_PRE();
#pragma unroll
        for (int i = 0; i < 4; ++i)
#pragma unroll
            for (int j = 0; j < 4; ++j)
                acc[i][j] = __builtin_amdgcn_mfma_f32_16x16x32_bf16(aF[i], bF[j], acc[i][j], 0, 0, 0);
        MFMA_POST();
        // ---- P2: ks0, i 4-7 ----
#pragma unroll
        for (int i = 0; i < 4; ++i) aF[i] = ldsw(bA, (i + 4) * 16 + fr, fq2);
        if (t + 1 < NT) IS_B(1, pn, t + 1);
        MFMA_PRE();
#pragma unroll
        for (int i = 0; i < 4; ++i)
#pragma unroll
            for (int j = 0; j < 4; ++j)
                acc[i + 4][j] = __builtin_amdgcn_mfma_f32_16x16x32_bf16(aF[i], bF[j], acc[i + 4][j], 0, 0, 0);
        MFMA_POST();
        // ---- P3: ks1, i 0-3 ----
#pragma unroll
        for (int i = 0; i < 4; ++i) aF[i] = ldsw(bA, i * 16 + fr, 64 + fq2);
#pragma unroll
        for (int j = 0; j < 4; ++j) bF[j] = ldsw(bB, wb + j * 16 + fr, 64 + fq2);
        MFMA_PRE();
#pragma unroll
        for (int i = 0; i < 4; ++i)
#pragma unroll
            for (int j = 0; j < 4; ++j)
                acc[i][j] = __builtin_amdgcn_mfma_f32_16x16x32_bf16(aF[i], bF[j], acc[i][j], 0, 0, 0);
        MFMA_POST();
        // ---- P4: ks1, i 4-7 ----
#pragma unroll
        for (int i = 0; i < 4; ++i) aF[i] = ldsw(bA, (i + 4) * 16 + fr, 64 + fq2);
        MFMA_PRE();
#pragma unroll
        for (int i = 0; i < 4; ++i)
#pragma unroll
            for (int j = 0; j < 4; ++j)
                acc[i + 4][j] = __builtin_amdgcn_mfma_f32_16x16x32_bf16(aF[i], bF[j], acc[i + 4][j], 0, 0, 0);
        MFMA_POST();
        // ---- boundary: issue A(t+2) into buf p (all tile-t reads done), counted wait ----
        if (t + 2 < NT) {
            IS_A(0, p, t + 2); IS_A(1, p, t + 2);
            asm volatile("s_waitcnt vmcnt(4)" ::: "memory");
            __builtin_amdgcn_s_barrier();
        } else if (t + 1 < NT) {
            asm volatile("s_waitcnt vmcnt(0)" ::: "memory");
            __builtin_amdgcn_s_barrier();
        }
    }

    // epilogue: wave-private LDS strips (32 rows x 64 cols), 128B-contiguous row stores.
    // C/D layout col=lane&15, row=(lane>>4)*4+r  [verified m89/m91]
    const int rq = fg * 4;
    float bvj[4];
#pragma unroll
    for (int j = 0; j < 4; ++j) bvj[j] = bs ? bs[bn * 256 + wc * 64 + j * 16 + fr] : 0.f;
    u16* strip = lds + wid * 2048;
    const int sr = lane >> 3, sc = lane & 7;
#pragma unroll
    for (int pass = 0; pass < 4; ++pass) {
#pragma unroll
        for (int ii = 0; ii < 2; ++ii) {
            const int i = pass * 2 + ii;
#pragma unroll
            for (int j = 0; j < 4; ++j)
#pragma unroll
                for (int r = 0; r < 4; ++r)
                    strip[(ii * 16 + rq + r) * 64 + j * 16 + fr] = f2b(acc[i][j][r] + bvj[j]);
        }
#pragma unroll
        for (int it = 0; it < 4; ++it) {
            const int lr = it * 8 + sr;
            uint4 v = *(const uint4*)(strip + lr * 64 + sc * 8);
            const int rl = bm * 256 + wr * 128 + pass * 32 + lr;
            if (rl < Mvalid) {
                const long grow = perm ? (long)(((rl & 2047) << 4) | (rl >> 11)) : (long)rl;
                *(uint4*)(Co + grow * ldc + bn * 256 + wc * 64 + sc * 8) = v;
            }
        }
    }
#undef IS_A
#undef IS_B
#undef MFMA_PRE
#undef MFMA_POST
}

// ---------------- attention: block = (s, head-half); MFMA scores + in-reg softmax ----------------
// XCD-aligned to qkv256's writes: rows for s were written by XCD bm&7 == s>>8,
// so map bx&7 == s>>8 -> qkv rows read from the local XCD's L2.
__global__ __launch_bounds__(256) void attn_kernel(u16* __restrict__ qkv) {
    __shared__ __align__(16) u16 sQ[16 * ATT_ST], sK[16 * ATT_ST], sV[16 * ATT_ST];
    __shared__ float sS[4][16][16];
    const int tid = threadIdx.x;
    const int bx  = blockIdx.x;
    const int xcd   = bx & 7;
    const int hh    = (bx >> 3) & 1;
    const int inner = bx >> 4;          // 0..255
    const int s = (xcd << 8) | inner;
    const u16* base = qkv + (long)s * 16 * QKV_LD + hh * 384;

#pragma unroll
    for (int it = 0; it < 9; it++) {
        const int i = it * 256 + tid;
        const int t = i / 768, rem = i % 768, l = rem / 48, c = rem % 48;
        const u16* src = base + (long)l * QKV_LD + t * E_DIM + c * 8;
        u16* dst = (t == 0 ? sQ : t == 1 ? sK : sV) + l * ATT_ST + c * 8;
        *(uint4*)dst = *(const uint4*)src;
    }
    __syncthreads();

    const int lane = tid & 63;
    const int w    = tid >> 6;
    const int fr   = lane & 15;
    const int fq   = (lane >> 4) * 8;
    floatx4 acc = {};
    const u16* qrow = sQ + fr * ATT_ST + w * DHEAD + fq;
    const u16* krow = sK + fr * ATT_ST + w * DHEAD + fq;
#pragma unroll
    for (int st = 0; st < 3; st++) {
        bf16x8 qa = *(const bf16x8*)(qrow + st * 32);
        bf16x8 kb = *(const bf16x8*)(krow + st * 32);
        acc = __builtin_amdgcn_mfma_f32_16x16x32_bf16(qa, kb, acc, 0, 0, 0);
    }
    const int rq = (lane >> 4) * 4;
#pragma unroll
    for (int r = 0; r < 4; r++) {
        float sc = acc[r] * 0.10206207261596577f;   // 1/sqrt(96)
        float mx = sc;
#pragma unroll
        for (int off = 8; off > 0; off >>= 1) mx = fmaxf(mx, __shfl_xor(mx, off));
        float e = __expf(sc - mx);
        float sum = e;
#pragma unroll
        for (int off = 8; off > 0; off >>= 1) sum += __shfl_xor(sum, off);
        sS[w][rq + r][fr] = e / sum;
    }
    __syncthreads();

#pragma unroll
    for (int j = 0; j < 3; j++) {
        const int task = j * 256 + tid;
        const int h = task / 192, rem = task % 192, ll = rem / 12, c = rem % 12;
        float a[8] = {};
#pragma unroll
        for (int mm = 0; mm < 16; mm++) {
            const float p = sS[h][ll][mm];
            uint4 vw = *(const uint4*)(sV + mm * ATT_ST + h * DHEAD + c * 8);
            axpy8(a, p, vw);
        }
        ushort4 o0, o1;
        o0.x = f2b(a[0]); o0.y = f2b(a[1]); o0.z = f2b(a[2]); o0.w = f2b(a[3]);
        o1.x = f2b(a[4]); o1.y = f2b(a[5]); o1.z = f2b(a[6]); o1.w = f2b(a[7]);
        u16* dst = qkv + ((long)s * 16 + ll) * QKV_LD + (hh * 4 + h) * DHEAD + c * 8;
        *(ushort4*)dst = o0;
        *(ushort4*)(dst + 4) = o1;
    }
}

// ---------------- MLP GEMM panel (BK=64): part[panel][row] = sum_n relu(ctx@G^T + c)[row,n]*w2[n] ----------------
// XCD-aligned to attn's ctx writes: block bm reads ctx rows for s in [8bm, 8bm+8),
// which attn wrote on XCD s>>8 = bm>>5 -> map bx so bx&7 == bm>>5.
__global__ __launch_bounds__(256) void mlp_gemm(const u16* __restrict__ A, int lda,
                                                const u16* __restrict__ G,
                                                const float* __restrict__ cbias,
                                                const float* __restrict__ w2,
                                                float* __restrict__ part) {
    __shared__ __align__(16) u16 sA[2 * 128 * 32];
    __shared__ __align__(16) u16 sB[2 * 128 * 32];
    __shared__ float rowsum[128];
    const int tid = threadIdx.x;
    const int bx  = blockIdx.x;
    const int xcd = bx & 7;
    const int q   = bx >> 3;       // 0..95
    const int bn  = q % 3;
    const int t   = q / 3;         // 0..31
    const int bm  = (xcd << 5) | t;
    if (tid < 128) rowsum[tid] = 0.f;
    const int lane = tid & 63;
    const int wid  = tid >> 6;
    const int wm   = (wid >> 1) * 64;
    const int wn   = (wid & 1) * 64;
    const int ar = tid >> 2;
    const int ac = (tid & 3) * 8;
    const u16* Ap = A + (long)(bm * 128 + ar) * lda + ac;
    const u16* Wp = G + (long)(bn * 128 + ar) * 768 + ac;
    const long a2 = (long)64 * lda;
    const long w2s = (long)64 * 768;
    const int fr = lane & 15;
    const int fq = (lane >> 4) * 8;
    const int rq = (lane >> 4) * 4;

    floatx4 acc[4][4] = {};
    for (int k0 = 0; k0 < 768; k0 += 64) {
#pragma unroll
        for (int h = 0; h < 2; h++) {
            GLDS(Ap + k0 + h * 32,       sA + h * 4096 + tid * 8);
            GLDS(Ap + a2 + k0 + h * 32,  sA + h * 4096 + 2048 + tid * 8);
            GLDS(Wp + k0 + h * 32,       sB + h * 4096 + tid * 8);
            GLDS(Wp + w2s + k0 + h * 32, sB + h * 4096 + 2048 + tid * 8);
        }
        __syncthreads();
#pragma unroll
        for (int h = 0; h < 2; h++) {
            bf16x8 aF[4], bF[4];
#pragma unroll
            for (int i = 0; i < 4; i++) {
                aF[i] = *(const bf16x8*)(sA + h * 4096 + (wm + i * 16 + fr) * 32 + fq);
                bF[i] = *(const bf16x8*)(sB + h * 4096 + (wn + i * 16 + fr) * 32 + fq);
            }
#pragma unroll
            for (int i = 0; i < 4; i++)
#pragma unroll
                for (int j = 0; j < 4; j++)
                    acc[i][j] = __builtin_amdgcn_mfma_f32_16x16x32_bf16(aF[i], bF[j], acc[i][j], 0, 0, 0);
        }
        __syncthreads();
    }
    float partl[4][4] = {};
#pragma unroll
    for (int j = 0; j < 4; j++) {
        const int col = bn * 128 + wn + j * 16 + fr;
        const float cv = cbias[col];
        const float wv = w2[col];
#pragma unroll
        for (int i = 0; i < 4; i++)
#pragma unroll
            for (int r = 0; r < 4; r++)
                partl[i][r] += fmaxf(acc[i][j][r] + cv, 0.f) * wv;
    }
#pragma unroll
    for (int i = 0; i < 4; i++)
#pragma unroll
        for (int r = 0; r < 4; r++) {
            float v = partl[i][r];
#pragma unroll
            for (int off = 8; off > 0; off >>= 1) v += __shfl_xor(v, off);
            if (fr == 0) atomicAdd(&rowsum[wm + i * 16 + rq + r], v);
        }
    __syncthreads();
    if (tid < 128) part[(long)bn * MROWS + bm * 128 + tid] = rowsum[tid];
}

// ---------------- broadcast: block = one s; 16 rows, nontemporal streaming stores ----------------
__global__ __launch_bounds__(256) void bcast_kernel(const float* __restrict__ part,
                                                    const float* __restrict__ b2,
                                                    float* __restrict__ out) {
    const int tid = threadIdx.x;
    const long s  = blockIdx.x;
    const float b2v = b2[0];
#pragma unroll
    for (int l = 0; l < 16; l++) {
        const long p = s * 16 + l;
        const float pv = part[p] + part[MROWS + p] + part[2 * MROWS + p] + b2v;
        floatx4 v4 = {pv, pv, pv, pv};
        floatx4* dst = (floatx4*)(out + ((long)l * S_DIM + s) * S_DIM);
        __builtin_nontemporal_store(v4, dst + tid);
        __builtin_nontemporal_store(v4, dst + tid + 256);
    }
}

extern "C" void kernel_launch(void* const* d_in, const int* in_sizes, int n_in,
                              void* d_out, int out_size, void* d_ws, size_t ws_size,
                              hipStream_t stream) {
    const float* features   = (const float*)d_in[0];
    const float* in_proj_b  = (const float*)d_in[2];
    const float* out_proj_b = (const float*)d_in[4];
    const float* b1 = (const float*)d_in[6];
    const float* w2 = (const float*)d_in[7];
    const float* b2 = (const float*)d_in[8];
    float* out = (float*)d_out;

    char* p = (char*)d_ws;
    u16* fbf = (u16*)p; p += (size_t)MROWS * E_DIM * 2;        // features bf16    50.3 MB
    u16* wib = (u16*)p; p += (size_t)QKV_LD * E_DIM * 2;       // in_proj_w bf16    3.5 MB
    u16* w1b = (u16*)p; p += (size_t)384 * E_DIM * 2;          // w1 bf16           0.6 MB
    u16* WoT = (u16*)p; p += (size_t)E_DIM * E_DIM * 2;        // out_proj_w^T bf16 1.2 MB
    u16* Gbf = (u16*)p; p += (size_t)384 * E_DIM * 2;          // G = W1@Wo bf16    0.6 MB
    float* cbuf  = (float*)p; p += 384 * 4;
    float* partb = (float*)p; p += (size_t)3 * MROWS * 4;      // per-panel row sums 384 KB
    p = (char*)(((size_t)p + 255) & ~(size_t)255);
    u16* qkv = (u16*)p; p += (size_t)MROWS * QKV_LD * 2;       // qkv bf16 (s-major) 151 MB
    u16* ctx = qkv;                                            // attention writes over q cols

    // merged prep (3 cvts + transpose + cbias)
    prep<<<PB4, 256, 0, stream>>>(features, (const float*)d_in[1], (const float*)d_in[5],
                                  (const float*)d_in[3], out_proj_b, b1,
                                  fbf, wib, w1b, WoT, cbuf);
    // 256x256 8-phase GEMM: qkv (1152 blocks) + G = W1@Wo (6 tail blocks)
    qkv256<<<1158, 512, 0, stream>>>(fbf, wib, in_proj_b, qkv, w1b, WoT, Gbf);
    // attention (in place into q-columns), XCD-aligned to qkv256 writes
    attn_kernel<<<S_DIM * 2, 256, 0, stream>>>(qkv);
    // MLP panels -> partial row sums, XCD-aligned to attn writes
    mlp_gemm<<<768, 256, 0, stream>>>(ctx, QKV_LD, Gbf, cbuf, w2, partb);
    // broadcast write
    bcast_kernel<<<S_DIM, 256, 0, stream>>>(partb, b2, out);
}

// Round 3
// 552.081 us; speedup vs baseline: 1.0598x; 1.0053x over previous
//
#include <hip/hip_runtime.h>

typedef unsigned short u16;
typedef __attribute__((ext_vector_type(8))) __bf16 bf16x8;
typedef __attribute__((ext_vector_type(4))) float floatx4;

#define B_DIM  16
#define S_DIM  2048
#define E_DIM  768
#define HEADS  8
#define DHEAD  96
#define MROWS  32768    // B_DIM * S_DIM
#define QKV_LD 2304     // 3*E_DIM
#define NT     12       // K tiles of 64 (K=768)

#define GLDS(gp, lp) __builtin_amdgcn_global_load_lds( \
    (const __attribute__((address_space(1))) void*)(gp), \
    (__attribute__((address_space(3))) void*)(lp), 16, 0, 0)

__device__ __forceinline__ u16 f2b(float f) {
    unsigned u = __float_as_uint(f);
    u += 0x7fffu + ((u >> 16) & 1u);   // RNE
    return (u16)(u >> 16);
}
__device__ __forceinline__ float blo(unsigned u) { return __uint_as_float(u << 16); }
__device__ __forceinline__ float bhi(unsigned u) { return __uint_as_float(u & 0xffff0000u); }

__device__ __forceinline__ void axpy8(float* acc, float p, uint4 v) {
    acc[0] += p * blo(v.x); acc[1] += p * bhi(v.x);
    acc[2] += p * blo(v.y); acc[3] += p * bhi(v.y);
    acc[4] += p * blo(v.z); acc[5] += p * bhi(v.z);
    acc[6] += p * blo(v.w); acc[7] += p * bhi(v.w);
}

// swizzled LDS fragment read: half_base is a [128][64] bf16 half-tile,
// physical chunk layout LDS[r][q] holds logical (r, q^(r&7))  (see staging)
__device__ __forceinline__ bf16x8 ldsw(const u16* half_base, int rowh, int cb) {
    return *(const bf16x8*)((const char*)half_base + rowh * 128 + (cb ^ ((rowh & 7) << 4)));
}

// ---------------- merged prep: cvt fbf / wib / w1b, transpose WoT, cbias ----------------
#define PB0 24576   // fbf cvt blocks   (32768*768/4/256)
#define PB1 26304   // + wib 1728       (2304*768/4/256)
#define PB2 26592   // + w1b 288        (384*768/4/256)
#define PB3 27168   // + transpose 576  (24*24)
#define PB4 27552   // + cbias 384
__global__ __launch_bounds__(256) void prep(const float* __restrict__ features,
                                            const float* __restrict__ in_proj_w,
                                            const float* __restrict__ w1,
                                            const float* __restrict__ out_proj_w,
                                            const float* __restrict__ bo,
                                            const float* __restrict__ b1,
                                            u16* __restrict__ fbf, u16* __restrict__ wib,
                                            u16* __restrict__ w1b, u16* __restrict__ WoT,
                                            float* __restrict__ cbuf) {
    __shared__ float tsh[32][33];
    const int b = blockIdx.x, tid = threadIdx.x;
    if (b < PB2) {   // the three fp32->bf16 copies
        const float* src; u16* dst; long i;
        if (b < PB0)      { src = features;  dst = fbf; i = (long)b * 256 + tid; }
        else if (b < PB1) { src = in_proj_w; dst = wib; i = (long)(b - PB0) * 256 + tid; }
        else              { src = w1;        dst = w1b; i = (long)(b - PB1) * 256 + tid; }
        float4 f = ((const float4*)src)[i];
        ushort4 r;
        r.x = f2b(f.x); r.y = f2b(f.y); r.z = f2b(f.z); r.w = f2b(f.w);
        ((ushort4*)dst)[i] = r;
    } else if (b < PB3) {   // 768x768 transpose+cvt of out_proj_w
        const int t = b - PB2;
        const int bxT = t % 24, byT = t / 24;
        const int tx = tid & 31, ty = tid >> 5;
        int x = bxT * 32 + tx;
        int y = byT * 32 + ty;
#pragma unroll
        for (int j = 0; j < 4; j++) tsh[ty + j * 8][tx] = out_proj_w[(long)(y + j * 8) * 768 + x];
        __syncthreads();
        x = byT * 32 + tx;
        y = bxT * 32 + ty;
#pragma unroll
        for (int j = 0; j < 4; j++) WoT[(long)(y + j * 8) * 768 + x] = f2b(tsh[tx][ty + j * 8]);
    } else {   // cbias: c[n] = b1[n] + W1[n,:]·bo
        const int n = b - PB3;
        const float* row = w1 + (long)n * 768;
        float s = row[tid] * bo[tid] + row[tid + 256] * bo[tid + 256] + row[tid + 512] * bo[tid + 512];
#pragma unroll
        for (int off = 32; off > 0; off >>= 1) s += __shfl_xor(s, off);
        if ((tid & 63) == 0) tsh[0][tid >> 6] = s;
        __syncthreads();
        if (tid == 0) cbuf[n] = tsh[0][0] + tsh[0][1] + tsh[0][2] + tsh[0][3] + b1[n];
    }
}

// ---------------- QKV (+G) GEMM: 256x256 tile, BK=64, 8-phase counted-vmcnt schedule ----------------
// Blocks [0,1152): qkv = features @ in_proj_w^T + b, s-major perm, XCD swizzle bm&7==xcd
//                  (so all rows of a given s, i.e. s>>8 group, are written by one XCD).
// Blocks [1152,1158): G = W1 @ Wo (M=384: second M-tile partial, stores guarded).
// Schedule (scheme T ledger, per thread 8 loads/tile):
//   boundary entering tile u: issue A-halves of u+1 (4 loads, buf freed by u-1's last
//   barrier), s_waitcnt vmcnt(4) -> everything older (all of tile u) landed, s_barrier.
//   P1 issues B0(u+1), P2 issues B1(u+1). A gets ~4-phase HBM cover; B is L2-resident.
//   Each phase: ds_read frags -> barrier -> lgkmcnt(0)+sched_barrier -> setprio(1),
//   16 MFMA, setprio(0) -> barrier.
// LDS swizzle: chunk q of row r stored from global chunk q^(r&7); reads XOR the byte
// addr with (r&7)<<4 -> 8 lanes per 4-bank group = conflict-free ds_read_b128.
__global__ __launch_bounds__(512, 2) void qkv256(const u16* __restrict__ A,
                                                 const u16* __restrict__ W,
                                                 const float* __restrict__ bias,
                                                 u16* __restrict__ Cout,
                                                 const u16* __restrict__ gA,
                                                 const u16* __restrict__ gW,
                                                 u16* __restrict__ gC) {
    __shared__ __align__(16) u16 lds[2 * 32768];   // 128 KiB: [p]{A:2x[128][64], B:2x[128][64]}
    const int tid = threadIdx.x;
    const int bx  = blockIdx.x;
    int bm, bn, ldc, Mvalid; const u16 *Aa, *Ww; const float* bs; u16* Co; bool perm;
    if (bx < 1152) {
        const int xcd = bx & 7;
        const int q   = bx >> 3;          // 0..143: 16 bm-groups x 9 bn (A-panel reuse per XCD)
        bn = q % 9;
        bm = (q / 9) * 8 + xcd;           // bm&7 == xcd
        Aa = A; Ww = W; bs = bias; Co = Cout; ldc = QKV_LD; perm = true; Mvalid = 1 << 30;
    } else {
        const int g = bx - 1152;
        bn = g % 3; bm = g / 3;           // M tiles: 2 (rows 256..511 partial), N tiles: 3
        Aa = gA; Ww = gW; bs = nullptr; Co = gC; ldc = 768; perm = false; Mvalid = 384;
    }
    // staging: chunk ci = ld*512+tid -> (row=ci>>3, q=ci&7); src chunk pre-swizzled q^(row&7)
    const int r0 = tid >> 3,        r1 = (tid + 512) >> 3;
    const int q0 = (tid & 7) ^ (r0 & 7), q1 = ((tid + 512) & 7) ^ (r1 & 7);
    const u16* pA0 = Aa + (long)(bm * 256 + r0) * 768 + q0 * 8;
    const u16* pA1 = Aa + (long)(bm * 256 + r1) * 768 + q1 * 8;
    const u16* pB0 = Ww + (long)(bn * 256 + r0) * 768 + q0 * 8;
    const u16* pB1 = Ww + (long)(bn * 256 + r1) * 768 + q1 * 8;
    u16* dA0 = lds + tid * 8;           // ld0 chunks  (+p*32768 +h*8192)
    u16* dA1 = lds + 4096 + tid * 8;    // ld1 chunks
    u16* dB0 = lds + 16384 + tid * 8;
    u16* dB1 = lds + 16384 + 4096 + tid * 8;

#define IS_A(h, p, t) do { \
    GLDS(pA0 + (h) * 98304 + (t) * 64, dA0 + (p) * 32768 + (h) * 8192); \
    GLDS(pA1 + (h) * 98304 + (t) * 64, dA1 + (p) * 32768 + (h) * 8192); } while (0)
#define IS_B(h, p, t) do { \
    GLDS(pB0 + (h) * 98304 + (t) * 64, dB0 + (p) * 32768 + (h) * 8192); \
    GLDS(pB1 + (h) * 98304 + (t) * 64, dB1 + (p) * 32768 + (h) * 8192); } while (0)
#define MFMA_PRE() do { \
    __builtin_amdgcn_s_barrier(); \
    asm volatile("s_waitcnt lgkmcnt(0)" ::: "memory"); \
    __builtin_amdgcn_sched_barrier(0); \
    __builtin_amdgcn_s_setprio(1); } while (0)
#define MFMA_POST() do { \
    __builtin_amdgcn_s_setprio(0); \
    __builtin_amdgcn_s_barrier(); } while (0)

    const int lane = tid & 63, wid = tid >> 6;
    const int wr = wid >> 2, wc = wid & 3;          // 2M x 4N waves, 128x64 per wave
    const int fr = lane & 15, fg = lane >> 4;
    const int fq2 = fg * 16;                        // ks0 col byte
    const int wb  = (wc & 1) * 64;                  // B row base within half
    const u16* bufA_base = lds + wr * 8192;
    const u16* bufB_base = lds + 16384 + (wc >> 1) * 8192;

    // prologue: tile0 complete + tile1 A-halves in flight
    IS_A(0, 0, 0); IS_A(1, 0, 0); IS_B(0, 0, 0); IS_B(1, 0, 0);
    IS_A(0, 1, 1); IS_A(1, 1, 1);
    asm volatile("s_waitcnt vmcnt(4)" ::: "memory");
    __builtin_amdgcn_s_barrier();

    floatx4 acc[8][4] = {};
#pragma unroll 2
    for (int t = 0; t < NT; ++t) {
        const int p = t & 1, pn = p ^ 1;
        const u16* bA = bufA_base + p * 32768;
        const u16* bB = bufB_base + p * 32768;
        bf16x8 aF[4], bF[4];
        // ---- P1: ks0, i 0-3 ----
#pragma unroll
        for (int i = 0; i < 4; ++i) aF[i] = ldsw(bA, i * 16 + fr, fq2);
#pragma unroll
        for (int j = 0; j < 4; ++j) bF[j] = ldsw(bB, wb + j * 16 + fr, fq2);
        if (t + 1 < NT) IS_B(0, pn, t + 1);
        MFMA_PRE();
#pragma unroll
        for (int i = 0; i < 4; ++i)
#pragma unroll
            for (int j = 0; j < 4; ++j)
                acc[i][j] = __builtin_amdgcn_mfma_f32_16x16x32_bf16(aF[i], bF[j], acc[i][j], 0, 0, 0);
        MFMA_POST();
        // ---- P2: ks0, i 4-7 ----
#pragma unroll
        for (int i = 0; i < 4; ++i) aF[i] = ldsw(bA, (i + 4) * 16 + fr, fq2);
        if (t + 1 < NT) IS_B(1, pn, t + 1);
        MFMA_PRE();
#pragma unroll
        for (int i = 0; i < 4; ++i)
#pragma unroll
            for (int j = 0; j < 4; ++j)
                acc[i + 4][j] = __builtin_amdgcn_mfma_f32_16x16x32_bf16(aF[i], bF[j], acc[i + 4][j], 0, 0, 0);
        MFMA_POST();
        // ---- P3: ks1, i 0-3 ----
#pragma unroll
        for (int i = 0; i < 4; ++i) aF[i] = ldsw(bA, i * 16 + fr, 64 + fq2);
#pragma unroll
        for (int j = 0; j < 4; ++j) bF[j] = ldsw(bB, wb + j * 16 + fr, 64 + fq2);
        MFMA_PRE();
#pragma unroll
        for (int i = 0; i < 4; ++i)
#pragma unroll
            for (int j = 0; j < 4; ++j)
                acc[i][j] = __builtin_amdgcn_mfma_f32_16x16x32_bf16(aF[i], bF[j], acc[i][j], 0, 0, 0);
        MFMA_POST();
        // ---- P4: ks1, i 4-7 ----
#pragma unroll
        for (int i = 0; i < 4; ++i) aF[i] = ldsw(bA, (i + 4) * 16 + fr, 64 + fq2);
        MFMA_PRE();
#pragma unroll
        for (int i = 0; i < 4; ++i)
#pragma unroll
            for (int j = 0; j < 4; ++j)
                acc[i + 4][j] = __builtin_amdgcn_mfma_f32_16x16x32_bf16(aF[i], bF[j], acc[i + 4][j], 0, 0, 0);
        MFMA_POST();
        // ---- boundary: issue A(t+2) into buf p (all tile-t reads done), counted wait ----
        if (t + 2 < NT) {
            IS_A(0, p, t + 2); IS_A(1, p, t + 2);
            asm volatile("s_waitcnt vmcnt(4)" ::: "memory");
            __builtin_amdgcn_s_barrier();
        } else if (t + 1 < NT) {
            asm volatile("s_waitcnt vmcnt(0)" ::: "memory");
            __builtin_amdgcn_s_barrier();
        }
    }

    // epilogue: wave-private LDS strips (32 rows x 64 cols, stride 72 u16 = 144 B:
    // 16B-aligned reads, and row->bank shift 4 so b16 writes are 4-way not 8-way).
    // C/D layout col=lane&15, row=(lane>>4)*4+r  [verified m89/m91]
    const int rq = fg * 4;
    float bvj[4];
#pragma unroll
    for (int j = 0; j < 4; ++j) bvj[j] = bs ? bs[bn * 256 + wc * 64 + j * 16 + fr] : 0.f;
    u16* strip = lds + wid * 2304;
    const int sr = lane >> 3, sc = lane & 7;
#pragma unroll
    for (int pass = 0; pass < 4; ++pass) {
#pragma unroll
        for (int ii = 0; ii < 2; ++ii) {
            const int i = pass * 2 + ii;
#pragma unroll
            for (int j = 0; j < 4; ++j)
#pragma unroll
                for (int r = 0; r < 4; ++r)
                    strip[(ii * 16 + rq + r) * 72 + j * 16 + fr] = f2b(acc[i][j][r] + bvj[j]);
        }
#pragma unroll
        for (int it = 0; it < 4; ++it) {
            const int lr = it * 8 + sr;
            uint4 v = *(const uint4*)(strip + lr * 72 + sc * 8);
            const int rl = bm * 256 + wr * 128 + pass * 32 + lr;
            if (rl < Mvalid) {
                const long grow = perm ? (long)(((rl & 2047) << 4) | (rl >> 11)) : (long)rl;
                *(uint4*)(Co + grow * ldc + bn * 256 + wc * 64 + sc * 8) = v;
            }
        }
    }
#undef IS_A
#undef IS_B
#undef MFMA_PRE
#undef MFMA_POST
}

// ---------------- attention: block = (s, head-half); MFMA scores + in-reg softmax ----------------
// XCD-aligned to qkv256's writes: rows for s were written by XCD bm&7 == s>>8,
// so map bx&7 == s>>8 -> qkv rows read from the local XCD's L2.
// Staging: global_load_lds direct (no reg round-trip), LINEAR LDS [3][16][48 chunks]
// with XOR-swizzled SOURCE chunk (c^(l&7)); all reads XOR the chunk index with (row&7)
// (rule #21: same involution on source and read). Q/K fragment reads land 8 lanes per
// 16B slot = conflict-free b128. LDS = 40960 B exactly -> 4 blocks/CU.
__global__ __launch_bounds__(256) void attn_kernel(u16* __restrict__ qkv) {
    __shared__ __align__(16) u16 sQKV[3 * 16 * 384];   // Q at 0, K at +6144, V at +12288
    __shared__ float sS[4][16][16];
    const int tid = threadIdx.x;
    const int bx  = blockIdx.x;
    const int xcd   = bx & 7;
    const int hh    = (bx >> 3) & 1;
    const int inner = bx >> 4;          // 0..255
    const int s = (xcd << 8) | inner;
    const u16* base = qkv + (long)s * 16 * QKV_LD + hh * 384;

#pragma unroll
    for (int it = 0; it < 9; it++) {
        const int id = it * 256 + tid;           // chunk id, LDS-linear
        const int t = id / 768, within = id % 768;
        const int l = within / 48, c = within % 48;
        const int csrc = c ^ (l & 7);            // pre-swizzled source chunk
        GLDS(base + (long)l * QKV_LD + t * E_DIM + csrc * 8, sQKV + id * 8);
    }
    __syncthreads();

    const int lane = tid & 63;
    const int w    = tid >> 6;
    const int fr   = lane & 15;
    const int fg   = lane >> 4;
    floatx4 acc = {};
#pragma unroll
    for (int st = 0; st < 3; st++) {
        const int ch  = w * 12 + st * 4 + fg;    // logical chunk in row
        const int chs = ch ^ (fr & 7);           // swizzled
        bf16x8 qa = *(const bf16x8*)(sQKV + fr * 384 + chs * 8);
        bf16x8 kb = *(const bf16x8*)(sQKV + 6144 + fr * 384 + chs * 8);
        acc = __builtin_amdgcn_mfma_f32_16x16x32_bf16(qa, kb, acc, 0, 0, 0);
    }
    const int rq = fg * 4;
#pragma unroll
    for (int r = 0; r < 4; r++) {
        float sc = acc[r] * 0.10206207261596577f;   // 1/sqrt(96)
        float mx = sc;
#pragma unroll
        for (int off = 8; off > 0; off >>= 1) mx = fmaxf(mx, __shfl_xor(mx, off));
        float e = __expf(sc - mx);
        float sum = e;
#pragma unroll
        for (int off = 8; off > 0; off >>= 1) sum += __shfl_xor(sum, off);
        sS[w][rq + r][fr] = e / sum;
    }
    __syncthreads();

#pragma unroll
    for (int j = 0; j < 3; j++) {
        const int task = j * 256 + tid;
        const int h = task / 192, rem = task % 192, ll = rem / 12, c = rem % 12;
        float a[8] = {};
#pragma unroll
        for (int mm = 0; mm < 16; mm++) {
            const float p = sS[h][ll][mm];
            const int ch = (h * 12 + c) ^ (mm & 7);
            uint4 vw = *(const uint4*)(sQKV + 12288 + mm * 384 + ch * 8);
            axpy8(a, p, vw);
        }
        uint4 o;
        o.x = (unsigned)f2b(a[0]) | ((unsigned)f2b(a[1]) << 16);
        o.y = (unsigned)f2b(a[2]) | ((unsigned)f2b(a[3]) << 16);
        o.z = (unsigned)f2b(a[4]) | ((unsigned)f2b(a[5]) << 16);
        o.w = (unsigned)f2b(a[6]) | ((unsigned)f2b(a[7]) << 16);
        *(uint4*)(qkv + ((long)s * 16 + ll) * QKV_LD + (hh * 4 + h) * DHEAD + c * 8) = o;
    }
}

// ---------------- MLP GEMM panel (BK=64): part[panel][row] = sum_n relu(ctx@G^T + c)[row,n]*w2[n] ----------------
// XCD-aligned to attn's ctx writes: block bm reads ctx rows for s in [8bm, 8bm+8),
// which attn wrote on XCD s>>8 = bm>>5 -> map bx so bx&7 == bm>>5.
__global__ __launch_bounds__(256) void mlp_gemm(const u16* __restrict__ A, int lda,
                                                const u16* __restrict__ G,
                                                const float* __restrict__ cbias,
                                                const float* __restrict__ w2,
                                                float* __restrict__ part) {
    __shared__ __align__(16) u16 sA[2 * 128 * 32];
    __shared__ __align__(16) u16 sB[2 * 128 * 32];
    __shared__ float rowsum[128];
    const int tid = threadIdx.x;
    const int bx  = blockIdx.x;
    const int xcd = bx & 7;
    const int q   = bx >> 3;       // 0..95
    const int bn  = q % 3;
    const int t   = q / 3;         // 0..31
    const int bm  = (xcd << 5) | t;
    if (tid < 128) rowsum[tid] = 0.f;
    const int lane = tid & 63;
    const int wid  = tid >> 6;
    const int wm   = (wid >> 1) * 64;
    const int wn   = (wid & 1) * 64;
    const int ar = tid >> 2;
    const int ac = (tid & 3) * 8;
    const u16* Ap = A + (long)(bm * 128 + ar) * lda + ac;
    const u16* Wp = G + (long)(bn * 128 + ar) * 768 + ac;
    const long a2 = (long)64 * lda;
    const long w2s = (long)64 * 768;
    const int fr = lane & 15;
    const int fq = (lane >> 4) * 8;
    const int rq = (lane >> 4) * 4;

    floatx4 acc[4][4] = {};
    for (int k0 = 0; k0 < 768; k0 += 64) {
#pragma unroll
        for (int h = 0; h < 2; h++) {
            GLDS(Ap + k0 + h * 32,       sA + h * 4096 + tid * 8);
            GLDS(Ap + a2 + k0 + h * 32,  sA + h * 4096 + 2048 + tid * 8);
            GLDS(Wp + k0 + h * 32,       sB + h * 4096 + tid * 8);
            GLDS(Wp + w2s + k0 + h * 32, sB + h * 4096 + 2048 + tid * 8);
        }
        __syncthreads();
#pragma unroll
        for (int h = 0; h < 2; h++) {
            bf16x8 aF[4], bF[4];
#pragma unroll
            for (int i = 0; i < 4; i++) {
                aF[i] = *(const bf16x8*)(sA + h * 4096 + (wm + i * 16 + fr) * 32 + fq);
                bF[i] = *(const bf16x8*)(sB + h * 4096 + (wn + i * 16 + fr) * 32 + fq);
            }
#pragma unroll
            for (int i = 0; i < 4; i++)
#pragma unroll
                for (int j = 0; j < 4; j++)
                    acc[i][j] = __builtin_amdgcn_mfma_f32_16x16x32_bf16(aF[i], bF[j], acc[i][j], 0, 0, 0);
        }
        __syncthreads();
    }
    float partl[4][4] = {};
#pragma unroll
    for (int j = 0; j < 4; j++) {
        const int col = bn * 128 + wn + j * 16 + fr;
        const float cv = cbias[col];
        const float wv = w2[col];
#pragma unroll
        for (int i = 0; i < 4; i++)
#pragma unroll
            for (int r = 0; r < 4; r++)
                partl[i][r] += fmaxf(acc[i][j][r] + cv, 0.f) * wv;
    }
#pragma unroll
    for (int i = 0; i < 4; i++)
#pragma unroll
        for (int r = 0; r < 4; r++) {
            float v = partl[i][r];
#pragma unroll
            for (int off = 8; off > 0; off >>= 1) v += __shfl_xor(v, off);
            if (fr == 0) atomicAdd(&rowsum[wm + i * 16 + rq + r], v);
        }
    __syncthreads();
    if (tid < 128) part[(long)bn * MROWS + bm * 128 + tid] = rowsum[tid];
}

// ---------------- broadcast: block = one s; 16 rows, nontemporal streaming stores ----------------
__global__ __launch_bounds__(256) void bcast_kernel(const float* __restrict__ part,
                                                    const float* __restrict__ b2,
                                                    float* __restrict__ out) {
    const int tid = threadIdx.x;
    const long s  = blockIdx.x;
    const float b2v = b2[0];
#pragma unroll
    for (int l = 0; l < 16; l++) {
        const long p = s * 16 + l;
        const float pv = part[p] + part[MROWS + p] + part[2 * MROWS + p] + b2v;
        floatx4 v4 = {pv, pv, pv, pv};
        floatx4* dst = (floatx4*)(out + ((long)l * S_DIM + s) * S_DIM);
        __builtin_nontemporal_store(v4, dst + tid);
        __builtin_nontemporal_store(v4, dst + tid + 256);
    }
}

extern "C" void kernel_launch(void* const* d_in, const int* in_sizes, int n_in,
                              void* d_out, int out_size, void* d_ws, size_t ws_size,
                              hipStream_t stream) {
    const float* features   = (const float*)d_in[0];
    const float* in_proj_b  = (const float*)d_in[2];
    const float* out_proj_b = (const float*)d_in[4];
    const float* b1 = (const float*)d_in[6];
    const float* w2 = (const float*)d_in[7];
    const float* b2 = (const float*)d_in[8];
    float* out = (float*)d_out;

    char* p = (char*)d_ws;
    u16* fbf = (u16*)p; p += (size_t)MROWS * E_DIM * 2;        // features bf16    50.3 MB
    u16* wib = (u16*)p; p += (size_t)QKV_LD * E_DIM * 2;       // in_proj_w bf16    3.5 MB
    u16* w1b = (u16*)p; p += (size_t)384 * E_DIM * 2;          // w1 bf16           0.6 MB
    u16* WoT = (u16*)p; p += (size_t)E_DIM * E_DIM * 2;        // out_proj_w^T bf16 1.2 MB
    u16* Gbf = (u16*)p; p += (size_t)384 * E_DIM * 2;          // G = W1@Wo bf16    0.6 MB
    float* cbuf  = (float*)p; p += 384 * 4;
    float* partb = (float*)p; p += (size_t)3 * MROWS * 4;      // per-panel row sums 384 KB
    p = (char*)(((size_t)p + 255) & ~(size_t)255);
    u16* qkv = (u16*)p; p += (size_t)MROWS * QKV_LD * 2;       // qkv bf16 (s-major) 151 MB
    u16* ctx = qkv;                                            // attention writes over q cols

    // merged prep (3 cvts + transpose + cbias)
    prep<<<PB4, 256, 0, stream>>>(features, (const float*)d_in[1], (const float*)d_in[5],
                                  (const float*)d_in[3], out_proj_b, b1,
                                  fbf, wib, w1b, WoT, cbuf);
    // 256x256 8-phase GEMM: qkv (1152 blocks) + G = W1@Wo (6 tail blocks)
    qkv256<<<1158, 512, 0, stream>>>(fbf, wib, in_proj_b, qkv, w1b, WoT, Gbf);
    // attention (in place into q-columns), XCD-aligned to qkv256 writes
    attn_kernel<<<S_DIM * 2, 256, 0, stream>>>(qkv);
    // MLP panels -> partial row sums, XCD-aligned to attn writes
    mlp_gemm<<<768, 256, 0, stream>>>(ctx, QKV_LD, Gbf, cbuf, w2, partb);
    // broadcast write
    bcast_kernel<<<S_DIM, 256, 0, stream>>>(partb, b2, out);
}

// Round 4
// 548.624 us; speedup vs baseline: 1.0665x; 1.0063x over previous
//
#include <hip/hip_runtime.h>

typedef unsigned short u16;
typedef __attribute__((ext_vector_type(8))) __bf16 bf16x8;
typedef __attribute__((ext_vector_type(4))) float floatx4;

#define B_DIM  16
#define S_DIM  2048
#define E_DIM  768
#define HEADS  8
#define DHEAD  96
#define MROWS  32768    // B_DIM * S_DIM
#define QKV_LD 2304     // 3*E_DIM
#define NT     12       // K tiles of 64 (K=768)

#define GLDS(gp, lp) __builtin_amdgcn_global_load_lds( \
    (const __attribute__((address_space(1))) void*)(gp), \
    (__attribute__((address_space(3))) void*)(lp), 16, 0, 0)

__device__ __forceinline__ u16 f2b(float f) {
    unsigned u = __float_as_uint(f);
    u += 0x7fffu + ((u >> 16) & 1u);   // RNE
    return (u16)(u >> 16);
}
__device__ __forceinline__ float blo(unsigned u) { return __uint_as_float(u << 16); }

// swizzled LDS fragment read: half_base is a [128][64] bf16 half-tile,
// physical chunk layout LDS[r][q] holds logical (r, q^(r&7))  (see staging)
__device__ __forceinline__ bf16x8 ldsw(const u16* half_base, int rowh, int cb) {
    return *(const bf16x8*)((const char*)half_base + rowh * 128 + (cb ^ ((rowh & 7) << 4)));
}

// ---------------- merged prep: cvt fbf / wib / w1b, transpose WoT, cbias ----------------
#define PB0 24576   // fbf cvt blocks   (32768*768/4/256)
#define PB1 26304   // + wib 1728       (2304*768/4/256)
#define PB2 26592   // + w1b 288        (384*768/4/256)
#define PB3 27168   // + transpose 576  (24*24)
#define PB4 27552   // + cbias 384
__global__ __launch_bounds__(256) void prep(const float* __restrict__ features,
                                            const float* __restrict__ in_proj_w,
                                            const float* __restrict__ w1,
                                            const float* __restrict__ out_proj_w,
                                            const float* __restrict__ bo,
                                            const float* __restrict__ b1,
                                            u16* __restrict__ fbf, u16* __restrict__ wib,
                                            u16* __restrict__ w1b, u16* __restrict__ WoT,
                                            float* __restrict__ cbuf) {
    __shared__ float tsh[32][33];
    const int b = blockIdx.x, tid = threadIdx.x;
    if (b < PB2) {   // the three fp32->bf16 copies
        const float* src; u16* dst; long i;
        if (b < PB0)      { src = features;  dst = fbf; i = (long)b * 256 + tid; }
        else if (b < PB1) { src = in_proj_w; dst = wib; i = (long)(b - PB0) * 256 + tid; }
        else              { src = w1;        dst = w1b; i = (long)(b - PB1) * 256 + tid; }
        float4 f = ((const float4*)src)[i];
        ushort4 r;
        r.x = f2b(f.x); r.y = f2b(f.y); r.z = f2b(f.z); r.w = f2b(f.w);
        ((ushort4*)dst)[i] = r;
    } else if (b < PB3) {   // 768x768 transpose+cvt of out_proj_w
        const int t = b - PB2;
        const int bxT = t % 24, byT = t / 24;
        const int tx = tid & 31, ty = tid >> 5;
        int x = bxT * 32 + tx;
        int y = byT * 32 + ty;
#pragma unroll
        for (int j = 0; j < 4; j++) tsh[ty + j * 8][tx] = out_proj_w[(long)(y + j * 8) * 768 + x];
        __syncthreads();
        x = byT * 32 + tx;
        y = bxT * 32 + ty;
#pragma unroll
        for (int j = 0; j < 4; j++) WoT[(long)(y + j * 8) * 768 + x] = f2b(tsh[tx][ty + j * 8]);
    } else {   // cbias: c[n] = b1[n] + W1[n,:]·bo
        const int n = b - PB3;
        const float* row = w1 + (long)n * 768;
        float s = row[tid] * bo[tid] + row[tid + 256] * bo[tid + 256] + row[tid + 512] * bo[tid + 512];
#pragma unroll
        for (int off = 32; off > 0; off >>= 1) s += __shfl_xor(s, off);
        if ((tid & 63) == 0) tsh[0][tid >> 6] = s;
        __syncthreads();
        if (tid == 0) cbuf[n] = tsh[0][0] + tsh[0][1] + tsh[0][2] + tsh[0][3] + b1[n];
    }
}

// ---------------- QKV (+G) GEMM: 256x256 tile, BK=64, 8-phase counted-vmcnt schedule ----------------
// Blocks [0,6): G = W1 @ Wo (run FIRST so they overlap the qkv wave, not a serial tail).
// Blocks [6,1158): qkv = features @ in_proj_w^T + b, s-major perm. Residue-corrected
//   index map keeps bm&7 == bx&7 (physical XCD, assuming XCD = blockIdx%8) so all rows
//   of a given s (s>>8 group) are written by one XCD -> attn reads local L2.
// Schedule (scheme T ledger, per thread 8 loads/tile):
//   boundary entering tile u: issue A-halves of u+1, s_waitcnt vmcnt(4) -> everything
//   older (all of tile u) landed, s_barrier. P1 issues B0(u+1), P2 issues B1(u+1).
//   A gets ~4-phase HBM cover; B is L2-resident. Each phase: ds_read frags -> barrier
//   -> lgkmcnt(0)+sched_barrier -> setprio(1), 16 MFMA, setprio(0) -> barrier.
// LDS swizzle: chunk q of row r stored from global chunk q^(r&7); reads XOR the byte
// addr with (r&7)<<4 -> 8 lanes per 4-bank group = conflict-free ds_read_b128.
__global__ __launch_bounds__(512, 2) void qkv256(const u16* __restrict__ A,
                                                 const u16* __restrict__ W,
                                                 const float* __restrict__ bias,
                                                 u16* __restrict__ Cout,
                                                 const u16* __restrict__ gA,
                                                 const u16* __restrict__ gW,
                                                 u16* __restrict__ gC) {
    __shared__ __align__(16) u16 lds[2 * 32768];   // 128 KiB: [p]{A:2x[128][64], B:2x[128][64]}
    const int tid = threadIdx.x;
    const int bx  = blockIdx.x;
    int bm, bn, ldc, Mvalid; const u16 *Aa, *Ww; const float* bs; u16* Co; bool perm;
    if (bx < 6) {            // G blocks first: overlap with the qkv wave
        bn = bx % 3; bm = bx / 3;         // M tiles: 2 (rows 256..511 partial), N tiles: 3
        Aa = gA; Ww = gW; bs = nullptr; Co = gC; ldc = 768; perm = false; Mvalid = 384;
    } else {
        const int xcd = bx & 7;
        const int q   = (bx >> 3) - ((bx & 7) < 6 ? 1 : 0);  // 0..143 per residue
        bn = q % 9;
        bm = (q / 9) * 8 + xcd;           // bm&7 == physical XCD
        Aa = A; Ww = W; bs = bias; Co = Cout; ldc = QKV_LD; perm = true; Mvalid = 1 << 30;
    }
    // staging: chunk ci = ld*512+tid -> (row=ci>>3, q=ci&7); src chunk pre-swizzled q^(row&7)
    const int r0 = tid >> 3,        r1 = (tid + 512) >> 3;
    const int q0 = (tid & 7) ^ (r0 & 7), q1 = ((tid + 512) & 7) ^ (r1 & 7);
    const u16* pA0 = Aa + (long)(bm * 256 + r0) * 768 + q0 * 8;
    const u16* pA1 = Aa + (long)(bm * 256 + r1) * 768 + q1 * 8;
    const u16* pB0 = Ww + (long)(bn * 256 + r0) * 768 + q0 * 8;
    const u16* pB1 = Ww + (long)(bn * 256 + r1) * 768 + q1 * 8;
    u16* dA0 = lds + tid * 8;           // ld0 chunks  (+p*32768 +h*8192)
    u16* dA1 = lds + 4096 + tid * 8;    // ld1 chunks
    u16* dB0 = lds + 16384 + tid * 8;
    u16* dB1 = lds + 16384 + 4096 + tid * 8;

#define IS_A(h, p, t) do { \
    GLDS(pA0 + (h) * 98304 + (t) * 64, dA0 + (p) * 32768 + (h) * 8192); \
    GLDS(pA1 + (h) * 98304 + (t) * 64, dA1 + (p) * 32768 + (h) * 8192); } while (0)
#define IS_B(h, p, t) do { \
    GLDS(pB0 + (h) * 98304 + (t) * 64, dB0 + (p) * 32768 + (h) * 8192); \
    GLDS(pB1 + (h) * 98304 + (t) * 64, dB1 + (p) * 32768 + (h) * 8192); } while (0)
#define MFMA_PRE() do { \
    __builtin_amdgcn_s_barrier(); \
    asm volatile("s_waitcnt lgkmcnt(0)" ::: "memory"); \
    __builtin_amdgcn_sched_barrier(0); \
    __builtin_amdgcn_s_setprio(1); } while (0)
#define MFMA_POST() do { \
    __builtin_amdgcn_s_setprio(0); \
    __builtin_amdgcn_s_barrier(); } while (0)

    const int lane = tid & 63, wid = tid >> 6;
    const int wr = wid >> 2, wc = wid & 3;          // 2M x 4N waves, 128x64 per wave
    const int fr = lane & 15, fg = lane >> 4;
    const int fq2 = fg * 16;                        // ks0 col byte
    const int wb  = (wc & 1) * 64;                  // B row base within half
    const u16* bufA_base = lds + wr * 8192;
    const u16* bufB_base = lds + 16384 + (wc >> 1) * 8192;

    // prologue: tile0 complete + tile1 A-halves in flight
    IS_A(0, 0, 0); IS_A(1, 0, 0); IS_B(0, 0, 0); IS_B(1, 0, 0);
    IS_A(0, 1, 1); IS_A(1, 1, 1);
    asm volatile("s_waitcnt vmcnt(4)" ::: "memory");
    __builtin_amdgcn_s_barrier();

    floatx4 acc[8][4] = {};
#pragma unroll 2
    for (int t = 0; t < NT; ++t) {
        const int p = t & 1, pn = p ^ 1;
        const u16* bA = bufA_base + p * 32768;
        const u16* bB = bufB_base + p * 32768;
        bf16x8 aF[4], bF[4];
        // ---- P1: ks0, i 0-3 ----
#pragma unroll
        for (int i = 0; i < 4; ++i) aF[i] = ldsw(bA, i * 16 + fr, fq2);
#pragma unroll
        for (int j = 0; j < 4; ++j) bF[j] = ldsw(bB, wb + j * 16 + fr, fq2);
        if (t + 1 < NT) IS_B(0, pn, t + 1);
        MFMA_PRE();
#pragma unroll
        for (int i = 0; i < 4; ++i)
#pragma unroll
            for (int j = 0; j < 4; ++j)
                acc[i][j] = __builtin_amdgcn_mfma_f32_16x16x32_bf16(aF[i], bF[j], acc[i][j], 0, 0, 0);
        MFMA_POST();
        // ---- P2: ks0, i 4-7 ----
#pragma unroll
        for (int i = 0; i < 4; ++i) aF[i] = ldsw(bA, (i + 4) * 16 + fr, fq2);
        if (t + 1 < NT) IS_B(1, pn, t + 1);
        MFMA_PRE();
#pragma unroll
        for (int i = 0; i < 4; ++i)
#pragma unroll
            for (int j = 0; j < 4; ++j)
                acc[i + 4][j] = __builtin_amdgcn_mfma_f32_16x16x32_bf16(aF[i], bF[j], acc[i + 4][j], 0, 0, 0);
        MFMA_POST();
        // ---- P3: ks1, i 0-3 ----
#pragma unroll
        for (int i = 0; i < 4; ++i) aF[i] = ldsw(bA, i * 16 + fr, 64 + fq2);
#pragma unroll
        for (int j = 0; j < 4; ++j) bF[j] = ldsw(bB, wb + j * 16 + fr, 64 + fq2);
        MFMA_PRE();
#pragma unroll
        for (int i = 0; i < 4; ++i)
#pragma unroll
            for (int j = 0; j < 4; ++j)
                acc[i][j] = __builtin_amdgcn_mfma_f32_16x16x32_bf16(aF[i], bF[j], acc[i][j], 0, 0, 0);
        MFMA_POST();
        // ---- P4: ks1, i 4-7 ----
#pragma unroll
        for (int i = 0; i < 4; ++i) aF[i] = ldsw(bA, (i + 4) * 16 + fr, 64 + fq2);
        MFMA_PRE();
#pragma unroll
        for (int i = 0; i < 4; ++i)
#pragma unroll
            for (int j = 0; j < 4; ++j)
                acc[i + 4][j] = __builtin_amdgcn_mfma_f32_16x16x32_bf16(aF[i], bF[j], acc[i + 4][j], 0, 0, 0);
        MFMA_POST();
        // ---- boundary: issue A(t+2) into buf p (all tile-t reads done), counted wait ----
        if (t + 2 < NT) {
            IS_A(0, p, t + 2); IS_A(1, p, t + 2);
            asm volatile("s_waitcnt vmcnt(4)" ::: "memory");
            __builtin_amdgcn_s_barrier();
        } else if (t + 1 < NT) {
            asm volatile("s_waitcnt vmcnt(0)" ::: "memory");
            __builtin_amdgcn_s_barrier();
        }
    }

    // epilogue: wave-private LDS strips (32 rows x 64 cols, stride 72 u16 = 144 B:
    // 16B-aligned reads, and row->bank shift 4 so b16 writes are 4-way not 8-way).
    // C/D layout col=lane&15, row=(lane>>4)*4+r  [verified m89/m91]
    const int rq = fg * 4;
    float bvj[4];
#pragma unroll
    for (int j = 0; j < 4; ++j) bvj[j] = bs ? bs[bn * 256 + wc * 64 + j * 16 + fr] : 0.f;
    u16* strip = lds + wid * 2304;
    const int sr = lane >> 3, sc = lane & 7;
#pragma unroll
    for (int pass = 0; pass < 4; ++pass) {
#pragma unroll
        for (int ii = 0; ii < 2; ++ii) {
            const int i = pass * 2 + ii;
#pragma unroll
            for (int j = 0; j < 4; ++j)
#pragma unroll
                for (int r = 0; r < 4; ++r)
                    strip[(ii * 16 + rq + r) * 72 + j * 16 + fr] = f2b(acc[i][j][r] + bvj[j]);
        }
#pragma unroll
        for (int it = 0; it < 4; ++it) {
            const int lr = it * 8 + sr;
            uint4 v = *(const uint4*)(strip + lr * 72 + sc * 8);
            const int rl = bm * 256 + wr * 128 + pass * 32 + lr;
            if (rl < Mvalid) {
                const long grow = perm ? (long)(((rl & 2047) << 4) | (rl >> 11)) : (long)rl;
                *(uint4*)(Co + grow * ldc + bn * 256 + wc * 64 + sc * 8) = v;
            }
        }
    }
#undef IS_A
#undef IS_B
#undef MFMA_PRE
#undef MFMA_POST
}

// ---------------- attention: block = (s, head-half); MFMA scores + MFMA PV ----------------
// XCD-aligned to qkv256's writes (bx&7 == s>>8 -> local-L2 reads).
// Staging: global_load_lds direct; Q/K source-chunk XOR-swizzled (row reads, rule #21
// both-sides involution); V staged LINEAR (PV reads V by COLUMNS: stride 768 B lands
// 2 lanes/bank = free, no swizzle needed).
// PV via MFMA with precision-preserving hi/lo split: A-frag holds Phi=bf16(P) in
// k=0..15 and Plo=bf16(P-Phi) in k=16..31; B-frag holds V duplicated in both k-halves
// -> D = sum (Phi+Plo)*V ~= fp32-P accuracy with fp32 accumulate.
// D staged into the dead Q-plane (exact size match: 16x384 u16), then one coalesced
// cooperative store. LDS = 40960 B -> 4 blocks/CU.
__global__ __launch_bounds__(256) void attn_kernel(u16* __restrict__ qkv) {
    __shared__ __align__(16) u16 sQKV[3 * 16 * 384];   // u16 idx: Q/ctx at 0, K at 6144, V at 12288
    __shared__ __align__(16) u16 sP[4][2][16][16];     // per-head {phi,plo} planes
    const int tid = threadIdx.x;
    const int bx  = blockIdx.x;
    const int xcd   = bx & 7;
    const int hh    = (bx >> 3) & 1;
    const int inner = bx >> 4;          // 0..255
    const int s = (xcd << 8) | inner;
    const u16* base = qkv + (long)s * 16 * QKV_LD + hh * 384;

#pragma unroll
    for (int it = 0; it < 9; it++) {
        const int id = it * 256 + tid;           // chunk id, LDS-linear
        const int t = id / 768, within = id % 768;
        const int l = within / 48, c = within % 48;
        const int csrc = (t < 2) ? (c ^ (l & 7)) : c;   // V linear for column reads
        GLDS(base + (long)l * QKV_LD + t * E_DIM + csrc * 8, sQKV + id * 8);
    }
    __syncthreads();

    const int lane = tid & 63;
    const int w    = tid >> 6;          // head within half
    const int fr   = lane & 15;
    const int fg   = lane >> 4;
    floatx4 acc = {};
#pragma unroll
    for (int st = 0; st < 3; st++) {
        const int ch  = w * 12 + st * 4 + fg;    // logical chunk in row
        const int chs = ch ^ (fr & 7);           // swizzled
        bf16x8 qa = *(const bf16x8*)(sQKV + fr * 384 + chs * 8);
        bf16x8 kb = *(const bf16x8*)(sQKV + 6144 + fr * 384 + chs * 8);
        acc = __builtin_amdgcn_mfma_f32_16x16x32_bf16(qa, kb, acc, 0, 0, 0);
    }
    const int rq = fg * 4;
#pragma unroll
    for (int r = 0; r < 4; r++) {
        float sc = acc[r] * 0.10206207261596577f;   // 1/sqrt(96)
        float mx = sc;
#pragma unroll
        for (int off = 8; off > 0; off >>= 1) mx = fmaxf(mx, __shfl_xor(mx, off));
        float e = __expf(sc - mx);
        float sum = e;
#pragma unroll
        for (int off = 8; off > 0; off >>= 1) sum += __shfl_xor(sum, off);
        const float pv = e / sum;
        const u16 phi = f2b(pv);
        const u16 plo = f2b(pv - blo((unsigned)phi));
        sP[w][0][rq + r][fr] = phi;
        sP[w][1][rq + r][fr] = plo;
    }
    // barrier: Q-plane reads (XOR'd chunks cross wave column bands) must finish
    // everywhere before any wave overwrites it with ctx; also publishes sP.
    __syncthreads();

    // P fragment: A[l][k] with k<16 -> Phi[l][k], k>=16 -> Plo[l][k-16].
    // lane(fr,fg) holds A[fr][fg*8+j] = sP[w][fg>>1][fr][(fg&1)*8 + j]  (one b128).
    const bf16x8 pfrag = *(const bf16x8*)(&sP[w][fg >> 1][fr][(fg & 1) * 8]);
    const int mbase = (fg & 1) * 8;
    u16* ctx = sQKV;    // reuse Q plane as ctx staging [16][384] u16
#pragma unroll
    for (int dt = 0; dt < 6; dt++) {
        const int d = w * 96 + dt * 16 + fr;     // global col within this hh-half
        const u16* vcol = sQKV + 12288 + mbase * 384 + d;
        unsigned vv0 = vcol[0 * 384], vv1 = vcol[1 * 384], vv2 = vcol[2 * 384], vv3 = vcol[3 * 384];
        unsigned vv4 = vcol[4 * 384], vv5 = vcol[5 * 384], vv6 = vcol[6 * 384], vv7 = vcol[7 * 384];
        unsigned pk0 = vv0 | (vv1 << 16), pk1 = vv2 | (vv3 << 16);
        unsigned pk2 = vv4 | (vv5 << 16), pk3 = vv6 | (vv7 << 16);
        uint4 pkv = {pk0, pk1, pk2, pk3};
        bf16x8 bfrag = *(const bf16x8*)&pkv;     // B[c=d][k] = V[(k&15... dup)(fg&1)*8+j][d]
        floatx4 o = {};
        o = __builtin_amdgcn_mfma_f32_16x16x32_bf16(pfrag, bfrag, o, 0, 0, 0);
#pragma unroll
        for (int r = 0; r < 4; r++) ctx[(rq + r) * 384 + d] = f2b(o[r]);
    }
    __syncthreads();

    // cooperative coalesced store of ctx into the q-columns of qkv
#pragma unroll
    for (int j = 0; j < 3; j++) {
        const int task = j * 256 + tid;
        const int l = task / 48, c = task % 48;
        uint4 v = *(const uint4*)(sQKV + l * 384 + c * 8);
        *(uint4*)(qkv + ((long)s * 16 + l) * QKV_LD + hh * 384 + c * 8) = v;
    }
}

// ---------------- MLP GEMM panel (BK=64): part[panel][row] = sum_n relu(ctx@G^T + c)[row,n]*w2[n] ----------------
// XCD-aligned to attn's ctx writes: block bm reads ctx rows for s in [8bm, 8bm+8),
// which attn wrote on XCD s>>8 = bm>>5 -> map bx so bx&7 == bm>>5.
__global__ __launch_bounds__(256) void mlp_gemm(const u16* __restrict__ A, int lda,
                                                const u16* __restrict__ G,
                                                const float* __restrict__ cbias,
                                                const float* __restrict__ w2,
                                                float* __restrict__ part) {
    __shared__ __align__(16) u16 sA[2 * 128 * 32];
    __shared__ __align__(16) u16 sB[2 * 128 * 32];
    __shared__ float rowsum[128];
    const int tid = threadIdx.x;
    const int bx  = blockIdx.x;
    const int xcd = bx & 7;
    const int q   = bx >> 3;       // 0..95
    const int bn  = q % 3;
    const int t   = q / 3;         // 0..31
    const int bm  = (xcd << 5) | t;
    if (tid < 128) rowsum[tid] = 0.f;
    const int lane = tid & 63;
    const int wid  = tid >> 6;
    const int wm   = (wid >> 1) * 64;
    const int wn   = (wid & 1) * 64;
    const int ar = tid >> 2;
    const int ac = (tid & 3) * 8;
    const u16* Ap = A + (long)(bm * 128 + ar) * lda + ac;
    const u16* Wp = G + (long)(bn * 128 + ar) * 768 + ac;
    const long a2 = (long)64 * lda;
    const long w2s = (long)64 * 768;
    const int fr = lane & 15;
    const int fq = (lane >> 4) * 8;
    const int rq = (lane >> 4) * 4;

    floatx4 acc[4][4] = {};
    for (int k0 = 0; k0 < 768; k0 += 64) {
#pragma unroll
        for (int h = 0; h < 2; h++) {
            GLDS(Ap + k0 + h * 32,       sA + h * 4096 + tid * 8);
            GLDS(Ap + a2 + k0 + h * 32,  sA + h * 4096 + 2048 + tid * 8);
            GLDS(Wp + k0 + h * 32,       sB + h * 4096 + tid * 8);
            GLDS(Wp + w2s + k0 + h * 32, sB + h * 4096 + 2048 + tid * 8);
        }
        __syncthreads();
#pragma unroll
        for (int h = 0; h < 2; h++) {
            bf16x8 aF[4], bF[4];
#pragma unroll
            for (int i = 0; i < 4; i++) {
                aF[i] = *(const bf16x8*)(sA + h * 4096 + (wm + i * 16 + fr) * 32 + fq);
                bF[i] = *(const bf16x8*)(sB + h * 4096 + (wn + i * 16 + fr) * 32 + fq);
            }
#pragma unroll
            for (int i = 0; i < 4; i++)
#pragma unroll
                for (int j = 0; j < 4; j++)
                    acc[i][j] = __builtin_amdgcn_mfma_f32_16x16x32_bf16(aF[i], bF[j], acc[i][j], 0, 0, 0);
        }
        __syncthreads();
    }
    float partl[4][4] = {};
#pragma unroll
    for (int j = 0; j < 4; j++) {
        const int col = bn * 128 + wn + j * 16 + fr;
        const float cv = cbias[col];
        const float wv = w2[col];
#pragma unroll
        for (int i = 0; i < 4; i++)
#pragma unroll
            for (int r = 0; r < 4; r++)
                partl[i][r] += fmaxf(acc[i][j][r] + cv, 0.f) * wv;
    }
#pragma unroll
    for (int i = 0; i < 4; i++)
#pragma unroll
        for (int r = 0; r < 4; r++) {
            float v = partl[i][r];
#pragma unroll
            for (int off = 8; off > 0; off >>= 1) v += __shfl_xor(v, off);
            if (fr == 0) atomicAdd(&rowsum[wm + i * 16 + rq + r], v);
        }
    __syncthreads();
    if (tid < 128) part[(long)bn * MROWS + bm * 128 + tid] = rowsum[tid];
}

// ---------------- broadcast: block = one s; 16 rows, nontemporal streaming stores ----------------
__global__ __launch_bounds__(256) void bcast_kernel(const float* __restrict__ part,
                                                    const float* __restrict__ b2,
                                                    float* __restrict__ out) {
    const int tid = threadIdx.x;
    const long s  = blockIdx.x;
    const float b2v = b2[0];
#pragma unroll
    for (int l = 0; l < 16; l++) {
        const long p = s * 16 + l;
        const float pv = part[p] + part[MROWS + p] + part[2 * MROWS + p] + b2v;
        floatx4 v4 = {pv, pv, pv, pv};
        floatx4* dst = (floatx4*)(out + ((long)l * S_DIM + s) * S_DIM);
        __builtin_nontemporal_store(v4, dst + tid);
        __builtin_nontemporal_store(v4, dst + tid + 256);
    }
}

extern "C" void kernel_launch(void* const* d_in, const int* in_sizes, int n_in,
                              void* d_out, int out_size, void* d_ws, size_t ws_size,
                              hipStream_t stream) {
    const float* features   = (const float*)d_in[0];
    const float* in_proj_b  = (const float*)d_in[2];
    const float* out_proj_b = (const float*)d_in[4];
    const float* b1 = (const float*)d_in[6];
    const float* w2 = (const float*)d_in[7];
    const float* b2 = (const float*)d_in[8];
    float* out = (float*)d_out;

    char* p = (char*)d_ws;
    u16* fbf = (u16*)p; p += (size_t)MROWS * E_DIM * 2;        // features bf16    50.3 MB
    u16* wib = (u16*)p; p += (size_t)QKV_LD * E_DIM * 2;       // in_proj_w bf16    3.5 MB
    u16* w1b = (u16*)p; p += (size_t)384 * E_DIM * 2;          // w1 bf16           0.6 MB
    u16* WoT = (u16*)p; p += (size_t)E_DIM * E_DIM * 2;        // out_proj_w^T bf16 1.2 MB
    u16* Gbf = (u16*)p; p += (size_t)384 * E_DIM * 2;          // G = W1@Wo bf16    0.6 MB
    float* cbuf  = (float*)p; p += 384 * 4;
    float* partb = (float*)p; p += (size_t)3 * MROWS * 4;      // per-panel row sums 384 KB
    p = (char*)(((size_t)p + 255) & ~(size_t)255);
    u16* qkv = (u16*)p; p += (size_t)MROWS * QKV_LD * 2;       // qkv bf16 (s-major) 151 MB
    u16* ctx = qkv;                                            // attention writes over q cols

    // merged prep (3 cvts + transpose + cbias)
    prep<<<PB4, 256, 0, stream>>>(features, (const float*)d_in[1], (const float*)d_in[5],
                                  (const float*)d_in[3], out_proj_b, b1,
                                  fbf, wib, w1b, WoT, cbuf);
    // 256x256 8-phase GEMM: G = W1@Wo (6 blocks, FIRST) + qkv (1152 blocks)
    qkv256<<<1158, 512, 0, stream>>>(fbf, wib, in_proj_b, qkv, w1b, WoT, Gbf);
    // attention (in place into q-columns), XCD-aligned to qkv256 writes
    attn_kernel<<<S_DIM * 2, 256, 0, stream>>>(qkv);
    // MLP panels -> partial row sums, XCD-aligned to attn writes
    mlp_gemm<<<768, 256, 0, stream>>>(ctx, QKV_LD, Gbf, cbuf, w2, partb);
    // broadcast write
    bcast_kernel<<<S_DIM, 256, 0, stream>>>(partb, b2, out);
}

// Round 5
// 546.297 us; speedup vs baseline: 1.0710x; 1.0043x over previous
//
#include <hip/hip_runtime.h>

typedef unsigned short u16;
typedef __attribute__((ext_vector_type(8))) __bf16 bf16x8;
typedef __attribute__((ext_vector_type(4))) float floatx4;

#define B_DIM  16
#define S_DIM  2048
#define E_DIM  768
#define HEADS  8
#define DHEAD  96
#define MROWS  32768    // B_DIM * S_DIM
#define QKV_LD 2304     // 3*E_DIM
#define NT     12       // K tiles of 64 (K=768)

#define GLDS(gp, lp) __builtin_amdgcn_global_load_lds( \
    (const __attribute__((address_space(1))) void*)(gp), \
    (__attribute__((address_space(3))) void*)(lp), 16, 0, 0)

__device__ __forceinline__ u16 f2b(float f) {
    unsigned u = __float_as_uint(f);
    u += 0x7fffu + ((u >> 16) & 1u);   // RNE
    return (u16)(u >> 16);
}
__device__ __forceinline__ float blo(unsigned u) { return __uint_as_float(u << 16); }

// swizzled LDS fragment read: half_base is a [128][64] bf16 half-tile,
// physical chunk layout LDS[r][q] holds logical (r, q^(r&7))  (see staging)
__device__ __forceinline__ bf16x8 ldsw(const u16* half_base, int rowh, int cb) {
    return *(const bf16x8*)((const char*)half_base + rowh * 128 + (cb ^ ((rowh & 7) << 4)));
}

// ---------------- merged prep: cvt fbf / wib / w1b, transpose WoT, cbias ----------------
#define PB0 24576   // fbf cvt blocks   (32768*768/4/256)
#define PB1 26304   // + wib 1728       (2304*768/4/256)
#define PB2 26592   // + w1b 288        (384*768/4/256)
#define PB3 27168   // + transpose 576  (24*24)
#define PB4 27552   // + cbias 384
__global__ __launch_bounds__(256) void prep(const float* __restrict__ features,
                                            const float* __restrict__ in_proj_w,
                                            const float* __restrict__ w1,
                                            const float* __restrict__ out_proj_w,
                                            const float* __restrict__ bo,
                                            const float* __restrict__ b1,
                                            u16* __restrict__ fbf, u16* __restrict__ wib,
                                            u16* __restrict__ w1b, u16* __restrict__ WoT,
                                            float* __restrict__ cbuf) {
    __shared__ float tsh[32][33];
    const int b = blockIdx.x, tid = threadIdx.x;
    if (b < PB2) {   // the three fp32->bf16 copies
        const float* src; u16* dst; long i;
        if (b < PB0)      { src = features;  dst = fbf; i = (long)b * 256 + tid; }
        else if (b < PB1) { src = in_proj_w; dst = wib; i = (long)(b - PB0) * 256 + tid; }
        else              { src = w1;        dst = w1b; i = (long)(b - PB1) * 256 + tid; }
        float4 f = ((const float4*)src)[i];
        ushort4 r;
        r.x = f2b(f.x); r.y = f2b(f.y); r.z = f2b(f.z); r.w = f2b(f.w);
        ((ushort4*)dst)[i] = r;
    } else if (b < PB3) {   // 768x768 transpose+cvt of out_proj_w
        const int t = b - PB2;
        const int bxT = t % 24, byT = t / 24;
        const int tx = tid & 31, ty = tid >> 5;
        int x = bxT * 32 + tx;
        int y = byT * 32 + ty;
#pragma unroll
        for (int j = 0; j < 4; j++) tsh[ty + j * 8][tx] = out_proj_w[(long)(y + j * 8) * 768 + x];
        __syncthreads();
        x = byT * 32 + tx;
        y = bxT * 32 + ty;
#pragma unroll
        for (int j = 0; j < 4; j++) WoT[(long)(y + j * 8) * 768 + x] = f2b(tsh[tx][ty + j * 8]);
    } else {   // cbias: c[n] = b1[n] + W1[n,:]·bo
        const int n = b - PB3;
        const float* row = w1 + (long)n * 768;
        float s = row[tid] * bo[tid] + row[tid + 256] * bo[tid + 256] + row[tid + 512] * bo[tid + 512];
#pragma unroll
        for (int off = 32; off > 0; off >>= 1) s += __shfl_xor(s, off);
        if ((tid & 63) == 0) tsh[0][tid >> 6] = s;
        __syncthreads();
        if (tid == 0) cbuf[n] = tsh[0][0] + tsh[0][1] + tsh[0][2] + tsh[0][3] + b1[n];
    }
}

// ---------------- QKV (+G) GEMM: 256x256 tile, BK=64, 8-phase counted-vmcnt schedule ----------------
// Blocks [0,6): G = W1 @ Wo. Blocks [6,1158): qkv = features @ in_proj_w^T + b, s-major
// perm; residue-corrected map keeps bm&7 == bx&7 (physical XCD) so all rows of a given
// s (s>>8 group) are written by one XCD -> attn reads local L2.
// Schedule (scheme T ledger, per thread 8 loads/tile):
//   boundary entering tile u: issue A-halves of u+1, s_waitcnt vmcnt(4) -> everything
//   older (all of tile u) landed, s_barrier. P1 issues B0(u+1), P2 issues B1(u+1).
//   Each phase: ds_read frags -> barrier -> lgkmcnt(0)+sched_barrier -> setprio(1),
//   16 MFMA, setprio(0) -> barrier.
// LDS swizzle: chunk q of row r stored from global chunk q^(r&7); reads XOR the byte
// addr with (r&7)<<4 -> 8 lanes per 4-bank group = conflict-free ds_read_b128.
__global__ __launch_bounds__(512, 2) void qkv256(const u16* __restrict__ A,
                                                 const u16* __restrict__ W,
                                                 const float* __restrict__ bias,
                                                 u16* __restrict__ Cout,
                                                 const u16* __restrict__ gA,
                                                 const u16* __restrict__ gW,
                                                 u16* __restrict__ gC) {
    __shared__ __align__(16) u16 lds[2 * 32768];   // 128 KiB: [p]{A:2x[128][64], B:2x[128][64]}
    const int tid = threadIdx.x;
    const int bx  = blockIdx.x;
    int bm, bn, ldc, Mvalid; const u16 *Aa, *Ww; const float* bs; u16* Co; bool perm;
    if (bx < 6) {            // G blocks (co-resident with the qkv wave)
        bn = bx % 3; bm = bx / 3;         // M tiles: 2 (rows 256..511 partial), N tiles: 3
        Aa = gA; Ww = gW; bs = nullptr; Co = gC; ldc = 768; perm = false; Mvalid = 384;
    } else {
        const int xcd = bx & 7;
        const int q   = (bx >> 3) - ((bx & 7) < 6 ? 1 : 0);  // 0..143 per residue
        bn = q % 9;
        bm = (q / 9) * 8 + xcd;           // bm&7 == physical XCD
        Aa = A; Ww = W; bs = bias; Co = Cout; ldc = QKV_LD; perm = true; Mvalid = 1 << 30;
    }
    // staging: chunk ci = ld*512+tid -> (row=ci>>3, q=ci&7); src chunk pre-swizzled q^(row&7)
    const int r0 = tid >> 3,        r1 = (tid + 512) >> 3;
    const int q0 = (tid & 7) ^ (r0 & 7), q1 = ((tid + 512) & 7) ^ (r1 & 7);
    const u16* pA0 = Aa + (long)(bm * 256 + r0) * 768 + q0 * 8;
    const u16* pA1 = Aa + (long)(bm * 256 + r1) * 768 + q1 * 8;
    const u16* pB0 = Ww + (long)(bn * 256 + r0) * 768 + q0 * 8;
    const u16* pB1 = Ww + (long)(bn * 256 + r1) * 768 + q1 * 8;
    u16* dA0 = lds + tid * 8;           // ld0 chunks  (+p*32768 +h*8192)
    u16* dA1 = lds + 4096 + tid * 8;    // ld1 chunks
    u16* dB0 = lds + 16384 + tid * 8;
    u16* dB1 = lds + 16384 + 4096 + tid * 8;

#define IS_A(h, p, t) do { \
    GLDS(pA0 + (h) * 98304 + (t) * 64, dA0 + (p) * 32768 + (h) * 8192); \
    GLDS(pA1 + (h) * 98304 + (t) * 64, dA1 + (p) * 32768 + (h) * 8192); } while (0)
#define IS_B(h, p, t) do { \
    GLDS(pB0 + (h) * 98304 + (t) * 64, dB0 + (p) * 32768 + (h) * 8192); \
    GLDS(pB1 + (h) * 98304 + (t) * 64, dB1 + (p) * 32768 + (h) * 8192); } while (0)
#define MFMA_PRE() do { \
    __builtin_amdgcn_s_barrier(); \
    asm volatile("s_waitcnt lgkmcnt(0)" ::: "memory"); \
    __builtin_amdgcn_sched_barrier(0); \
    __builtin_amdgcn_s_setprio(1); } while (0)
#define MFMA_POST() do { \
    __builtin_amdgcn_s_setprio(0); \
    __builtin_amdgcn_s_barrier(); } while (0)

    const int lane = tid & 63, wid = tid >> 6;
    const int wr = wid >> 2, wc = wid & 3;          // 2M x 4N waves, 128x64 per wave
    const int fr = lane & 15, fg = lane >> 4;
    const int fq2 = fg * 16;                        // ks0 col byte
    const int wb  = (wc & 1) * 64;                  // B row base within half
    const u16* bufA_base = lds + wr * 8192;
    const u16* bufB_base = lds + 16384 + (wc >> 1) * 8192;

    // prologue: tile0 complete + tile1 A-halves in flight
    IS_A(0, 0, 0); IS_A(1, 0, 0); IS_B(0, 0, 0); IS_B(1, 0, 0);
    IS_A(0, 1, 1); IS_A(1, 1, 1);
    asm volatile("s_waitcnt vmcnt(4)" ::: "memory");
    __builtin_amdgcn_s_barrier();

    floatx4 acc[8][4] = {};
#pragma unroll 2
    for (int t = 0; t < NT; ++t) {
        const int p = t & 1, pn = p ^ 1;
        const u16* bA = bufA_base + p * 32768;
        const u16* bB = bufB_base + p * 32768;
        bf16x8 aF[4], bF[4];
        // ---- P1: ks0, i 0-3 ----
#pragma unroll
        for (int i = 0; i < 4; ++i) aF[i] = ldsw(bA, i * 16 + fr, fq2);
#pragma unroll
        for (int j = 0; j < 4; ++j) bF[j] = ldsw(bB, wb + j * 16 + fr, fq2);
        if (t + 1 < NT) IS_B(0, pn, t + 1);
        MFMA_PRE();
#pragma unroll
        for (int i = 0; i < 4; ++i)
#pragma unroll
            for (int j = 0; j < 4; ++j)
                acc[i][j] = __builtin_amdgcn_mfma_f32_16x16x32_bf16(aF[i], bF[j], acc[i][j], 0, 0, 0);
        MFMA_POST();
        // ---- P2: ks0, i 4-7 ----
#pragma unroll
        for (int i = 0; i < 4; ++i) aF[i] = ldsw(bA, (i + 4) * 16 + fr, fq2);
        if (t + 1 < NT) IS_B(1, pn, t + 1);
        MFMA_PRE();
#pragma unroll
        for (int i = 0; i < 4; ++i)
#pragma unroll
            for (int j = 0; j < 4; ++j)
                acc[i + 4][j] = __builtin_amdgcn_mfma_f32_16x16x32_bf16(aF[i], bF[j], acc[i + 4][j], 0, 0, 0);
        MFMA_POST();
        // ---- P3: ks1, i 0-3 ----
#pragma unroll
        for (int i = 0; i < 4; ++i) aF[i] = ldsw(bA, i * 16 + fr, 64 + fq2);
#pragma unroll
        for (int j = 0; j < 4; ++j) bF[j] = ldsw(bB, wb + j * 16 + fr, 64 + fq2);
        MFMA_PRE();
#pragma unroll
        for (int i = 0; i < 4; ++i)
#pragma unroll
            for (int j = 0; j < 4; ++j)
                acc[i][j] = __builtin_amdgcn_mfma_f32_16x16x32_bf16(aF[i], bF[j], acc[i][j], 0, 0, 0);
        MFMA_POST();
        // ---- P4: ks1, i 4-7 ----
#pragma unroll
        for (int i = 0; i < 4; ++i) aF[i] = ldsw(bA, (i + 4) * 16 + fr, 64 + fq2);
        MFMA_PRE();
#pragma unroll
        for (int i = 0; i < 4; ++i)
#pragma unroll
            for (int j = 0; j < 4; ++j)
                acc[i + 4][j] = __builtin_amdgcn_mfma_f32_16x16x32_bf16(aF[i], bF[j], acc[i + 4][j], 0, 0, 0);
        MFMA_POST();
        // ---- boundary: issue A(t+2) into buf p (all tile-t reads done), counted wait ----
        if (t + 2 < NT) {
            IS_A(0, p, t + 2); IS_A(1, p, t + 2);
            asm volatile("s_waitcnt vmcnt(4)" ::: "memory");
            __builtin_amdgcn_s_barrier();
        } else if (t + 1 < NT) {
            asm volatile("s_waitcnt vmcnt(0)" ::: "memory");
            __builtin_amdgcn_s_barrier();
        }
    }

    // epilogue: wave-private LDS strips (32 rows x 64 cols, stride 72 u16 = 144 B:
    // 16B-aligned reads, and row->bank shift 4 so b16 writes are 4-way not 8-way).
    // C/D layout col=lane&15, row=(lane>>4)*4+r  [verified m89/m91]
    const int rq = fg * 4;
    float bvj[4];
#pragma unroll
    for (int j = 0; j < 4; ++j) bvj[j] = bs ? bs[bn * 256 + wc * 64 + j * 16 + fr] : 0.f;
    u16* strip = lds + wid * 2304;
    const int sr = lane >> 3, sc = lane & 7;
#pragma unroll
    for (int pass = 0; pass < 4; ++pass) {
#pragma unroll
        for (int ii = 0; ii < 2; ++ii) {
            const int i = pass * 2 + ii;
#pragma unroll
            for (int j = 0; j < 4; ++j)
#pragma unroll
                for (int r = 0; r < 4; ++r)
                    strip[(ii * 16 + rq + r) * 72 + j * 16 + fr] = f2b(acc[i][j][r] + bvj[j]);
        }
#pragma unroll
        for (int it = 0; it < 4; ++it) {
            const int lr = it * 8 + sr;
            uint4 v = *(const uint4*)(strip + lr * 72 + sc * 8);
            const int rl = bm * 256 + wr * 128 + pass * 32 + lr;
            if (rl < Mvalid) {
                const long grow = perm ? (long)(((rl & 2047) << 4) | (rl >> 11)) : (long)rl;
                *(uint4*)(Co + grow * ldc + bn * 256 + wc * 64 + sc * 8) = v;
            }
        }
    }
#undef IS_A
#undef IS_B
#undef MFMA_PRE
#undef MFMA_POST
}

// ---------------- attention: block = (s, head-half); MFMA scores + MFMA PV ----------------
// XCD-aligned to qkv256's writes (bx&7 == s>>8 -> local-L2 reads).
// Staging: global_load_lds direct; Q/K source-chunk XOR-swizzled (row reads, rule #21
// both-sides involution); V staged LINEAR (PV reads V by COLUMNS: stride 768 B lands
// 2 lanes/bank = free, no swizzle needed).
// PV via MFMA with precision-preserving hi/lo split: A-frag holds Phi=bf16(P) in
// k=0..15 and Plo=bf16(P-Phi) in k=16..31; B-frag holds V duplicated in both k-halves
// -> D = sum (Phi+Plo)*V ~= fp32-P accuracy with fp32 accumulate.
// D staged into the dead Q-plane (exact size match: 16x384 u16), then one coalesced
// cooperative store. LDS = 40960 B -> 4 blocks/CU.
__global__ __launch_bounds__(256) void attn_kernel(u16* __restrict__ qkv) {
    __shared__ __align__(16) u16 sQKV[3 * 16 * 384];   // u16 idx: Q/ctx at 0, K at 6144, V at 12288
    __shared__ __align__(16) u16 sP[4][2][16][16];     // per-head {phi,plo} planes
    const int tid = threadIdx.x;
    const int bx  = blockIdx.x;
    const int xcd   = bx & 7;
    const int hh    = (bx >> 3) & 1;
    const int inner = bx >> 4;          // 0..255
    const int s = (xcd << 8) | inner;
    const u16* base = qkv + (long)s * 16 * QKV_LD + hh * 384;

#pragma unroll
    for (int it = 0; it < 9; it++) {
        const int id = it * 256 + tid;           // chunk id, LDS-linear
        const int t = id / 768, within = id % 768;
        const int l = within / 48, c = within % 48;
        const int csrc = (t < 2) ? (c ^ (l & 7)) : c;   // V linear for column reads
        GLDS(base + (long)l * QKV_LD + t * E_DIM + csrc * 8, sQKV + id * 8);
    }
    __syncthreads();

    const int lane = tid & 63;
    const int w    = tid >> 6;          // head within half
    const int fr   = lane & 15;
    const int fg   = lane >> 4;
    floatx4 acc = {};
#pragma unroll
    for (int st = 0; st < 3; st++) {
        const int ch  = w * 12 + st * 4 + fg;    // logical chunk in row
        const int chs = ch ^ (fr & 7);           // swizzled
        bf16x8 qa = *(const bf16x8*)(sQKV + fr * 384 + chs * 8);
        bf16x8 kb = *(const bf16x8*)(sQKV + 6144 + fr * 384 + chs * 8);
        acc = __builtin_amdgcn_mfma_f32_16x16x32_bf16(qa, kb, acc, 0, 0, 0);
    }
    const int rq = fg * 4;
#pragma unroll
    for (int r = 0; r < 4; r++) {
        float sc = acc[r] * 0.10206207261596577f;   // 1/sqrt(96)
        float mx = sc;
#pragma unroll
        for (int off = 8; off > 0; off >>= 1) mx = fmaxf(mx, __shfl_xor(mx, off));
        float e = __expf(sc - mx);
        float sum = e;
#pragma unroll
        for (int off = 8; off > 0; off >>= 1) sum += __shfl_xor(sum, off);
        const float pv = e / sum;
        const u16 phi = f2b(pv);
        const u16 plo = f2b(pv - blo((unsigned)phi));
        sP[w][0][rq + r][fr] = phi;
        sP[w][1][rq + r][fr] = plo;
    }
    // barrier: Q-plane reads (XOR'd chunks cross wave column bands) must finish
    // everywhere before any wave overwrites it with ctx; also publishes sP.
    __syncthreads();

    // P fragment: A[l][k] with k<16 -> Phi[l][k], k>=16 -> Plo[l][k-16].
    // lane(fr,fg) holds A[fr][fg*8+j] = sP[w][fg>>1][fr][(fg&1)*8 + j]  (one b128).
    const bf16x8 pfrag = *(const bf16x8*)(&sP[w][fg >> 1][fr][(fg & 1) * 8]);
    const int mbase = (fg & 1) * 8;
    u16* ctx = sQKV;    // reuse Q plane as ctx staging [16][384] u16
#pragma unroll
    for (int dt = 0; dt < 6; dt++) {
        const int d = w * 96 + dt * 16 + fr;     // global col within this hh-half
        const u16* vcol = sQKV + 12288 + mbase * 384 + d;
        unsigned vv0 = vcol[0 * 384], vv1 = vcol[1 * 384], vv2 = vcol[2 * 384], vv3 = vcol[3 * 384];
        unsigned vv4 = vcol[4 * 384], vv5 = vcol[5 * 384], vv6 = vcol[6 * 384], vv7 = vcol[7 * 384];
        unsigned pk0 = vv0 | (vv1 << 16), pk1 = vv2 | (vv3 << 16);
        unsigned pk2 = vv4 | (vv5 << 16), pk3 = vv6 | (vv7 << 16);
        uint4 pkv = {pk0, pk1, pk2, pk3};
        bf16x8 bfrag = *(const bf16x8*)&pkv;     // B[c=d][k] = V[(k&15... dup)(fg&1)*8+j][d]
        floatx4 o = {};
        o = __builtin_amdgcn_mfma_f32_16x16x32_bf16(pfrag, bfrag, o, 0, 0, 0);
#pragma unroll
        for (int r = 0; r < 4; r++) ctx[(rq + r) * 384 + d] = f2b(o[r]);
    }
    __syncthreads();

    // cooperative coalesced store of ctx into the q-columns of qkv
#pragma unroll
    for (int j = 0; j < 3; j++) {
        const int task = j * 256 + tid;
        const int l = task / 48, c = task % 48;
        uint4 v = *(const uint4*)(sQKV + l * 384 + c * 8);
        *(uint4*)(qkv + ((long)s * 16 + l) * QKV_LD + hh * 384 + c * 8) = v;
    }
}

// ---------------- MLP GEMM, 256x256 8-phase port ----------------
// part[panel][row] = sum_n relu(ctx@G^T + c)[row, n] * w2[n], panels bn in {0,1}.
// M=32768 (ctx rows, stride QKV_LD), N=384 (G rows; bn=1 half-valid, G padded to 512
// rows so staging reads stay in-workspace; invalid cols killed by select, not *0,
// so poison NaN can't propagate). Grid = 128 bm x 2 bn = 256 blocks = exactly one
// round at 1 block/CU (no tail quantization). XCD map: bm>>4 == physical XCD == s>>8
// (attn's writer XCD) -> ctx rows read from local L2.
__global__ __launch_bounds__(512, 2) void mlp256(const u16* __restrict__ A,
                                                 const u16* __restrict__ G,
                                                 const float* __restrict__ cbias,
                                                 const float* __restrict__ w2,
                                                 float* __restrict__ part) {
    __shared__ __align__(16) u16 lds[2 * 32768];
    __shared__ float rowsum[256];
    const int tid = threadIdx.x;
    const int bx  = blockIdx.x;
    const int xcd = bx & 7;
    const int q   = bx >> 3;            // 0..31
    const int bm  = xcd * 16 + (q >> 1);
    const int bn  = q & 1;
    // staging: chunk ci = ld*512+tid -> (row=ci>>3, q=ci&7); src chunk pre-swizzled q^(row&7)
    const int r0 = tid >> 3,        r1 = (tid + 512) >> 3;
    const int q0 = (tid & 7) ^ (r0 & 7), q1 = ((tid + 512) & 7) ^ (r1 & 7);
    const u16* pA0 = A + (long)(bm * 256 + r0) * QKV_LD + q0 * 8;
    const u16* pA1 = A + (long)(bm * 256 + r1) * QKV_LD + q1 * 8;
    const u16* pB0 = G + (long)(bn * 256 + r0) * 768 + q0 * 8;
    const u16* pB1 = G + (long)(bn * 256 + r1) * 768 + q1 * 8;
    u16* dA0 = lds + tid * 8;
    u16* dA1 = lds + 4096 + tid * 8;
    u16* dB0 = lds + 16384 + tid * 8;
    u16* dB1 = lds + 16384 + 4096 + tid * 8;

#define IS_A(h, p, t) do { \
    GLDS(pA0 + (h) * (128L * QKV_LD) + (t) * 64, dA0 + (p) * 32768 + (h) * 8192); \
    GLDS(pA1 + (h) * (128L * QKV_LD) + (t) * 64, dA1 + (p) * 32768 + (h) * 8192); } while (0)
#define IS_B(h, p, t) do { \
    GLDS(pB0 + (h) * 98304 + (t) * 64, dB0 + (p) * 32768 + (h) * 8192); \
    GLDS(pB1 + (h) * 98304 + (t) * 64, dB1 + (p) * 32768 + (h) * 8192); } while (0)
#define MFMA_PRE() do { \
    __builtin_amdgcn_s_barrier(); \
    asm volatile("s_waitcnt lgkmcnt(0)" ::: "memory"); \
    __builtin_amdgcn_sched_barrier(0); \
    __builtin_amdgcn_s_setprio(1); } while (0)
#define MFMA_POST() do { \
    __builtin_amdgcn_s_setprio(0); \
    __builtin_amdgcn_s_barrier(); } while (0)

    const int lane = tid & 63, wid = tid >> 6;
    const int wr = wid >> 2, wc = wid & 3;
    const int fr = lane & 15, fg = lane >> 4;
    const int fq2 = fg * 16;
    const int wb  = (wc & 1) * 64;
    const u16* bufA_base = lds + wr * 8192;
    const u16* bufB_base = lds + 16384 + (wc >> 1) * 8192;

    IS_A(0, 0, 0); IS_A(1, 0, 0); IS_B(0, 0, 0); IS_B(1, 0, 0);
    IS_A(0, 1, 1); IS_A(1, 1, 1);
    asm volatile("s_waitcnt vmcnt(4)" ::: "memory");
    __builtin_amdgcn_s_barrier();

    floatx4 acc[8][4] = {};
#pragma unroll 2
    for (int t = 0; t < NT; ++t) {
        const int p = t & 1, pn = p ^ 1;
        const u16* bA = bufA_base + p * 32768;
        const u16* bB = bufB_base + p * 32768;
        bf16x8 aF[4], bF[4];
#pragma unroll
        for (int i = 0; i < 4; ++i) aF[i] = ldsw(bA, i * 16 + fr, fq2);
#pragma unroll
        for (int j = 0; j < 4; ++j) bF[j] = ldsw(bB, wb + j * 16 + fr, fq2);
        if (t + 1 < NT) IS_B(0, pn, t + 1);
        MFMA_PRE();
#pragma unroll
        for (int i = 0; i < 4; ++i)
#pragma unroll
            for (int j = 0; j < 4; ++j)
                acc[i][j] = __builtin_amdgcn_mfma_f32_16x16x32_bf16(aF[i], bF[j], acc[i][j], 0, 0, 0);
        MFMA_POST();
#pragma unroll
        for (int i = 0; i < 4; ++i) aF[i] = ldsw(bA, (i + 4) * 16 + fr, fq2);
        if (t + 1 < NT) IS_B(1, pn, t + 1);
        MFMA_PRE();
#pragma unroll
        for (int i = 0; i < 4; ++i)
#pragma unroll
            for (int j = 0; j < 4; ++j)
                acc[i + 4][j] = __builtin_amdgcn_mfma_f32_16x16x32_bf16(aF[i], bF[j], acc[i + 4][j], 0, 0, 0);
        MFMA_POST();
#pragma unroll
        for (int i = 0; i < 4; ++i) aF[i] = ldsw(bA, i * 16 + fr, 64 + fq2);
#pragma unroll
        for (int j = 0; j < 4; ++j) bF[j] = ldsw(bB, wb + j * 16 + fr, 64 + fq2);
        MFMA_PRE();
#pragma unroll
        for (int i = 0; i < 4; ++i)
#pragma unroll
            for (int j = 0; j < 4; ++j)
                acc[i][j] = __builtin_amdgcn_mfma_f32_16x16x32_bf16(aF[i], bF[j], acc[i][j], 0, 0, 0);
        MFMA_POST();
#pragma unroll
        for (int i = 0; i < 4; ++i) aF[i] = ldsw(bA, (i + 4) * 16 + fr, 64 + fq2);
        MFMA_PRE();
#pragma unroll
        for (int i = 0; i < 4; ++i)
#pragma unroll
            for (int j = 0; j < 4; ++j)
                acc[i + 4][j] = __builtin_amdgcn_mfma_f32_16x16x32_bf16(aF[i], bF[j], acc[i + 4][j], 0, 0, 0);
        MFMA_POST();
        if (t + 2 < NT) {
            IS_A(0, p, t + 2); IS_A(1, p, t + 2);
            asm volatile("s_waitcnt vmcnt(4)" ::: "memory");
            __builtin_amdgcn_s_barrier();
        } else if (t + 1 < NT) {
            asm volatile("s_waitcnt vmcnt(0)" ::: "memory");
            __builtin_amdgcn_s_barrier();
        }
    }

    // fused epilogue: rowsum[row] += sum_cols relu(acc + cbias) * w2, then part write.
    // Rows: bm*256 + wr*128 + i*16 + fg*4 + r; cols: bn*256 + wc*64 + j*16 + fr.
    if (tid < 256) rowsum[tid] = 0.f;
    __syncthreads();
    float partl[8][4] = {};
#pragma unroll
    for (int j = 0; j < 4; ++j) {
        const int col = bn * 256 + wc * 64 + j * 16 + fr;
        const bool valid = col < 384;
        const float cv = valid ? cbias[col] : 0.f;
        const float wv = valid ? w2[col] : 0.f;
#pragma unroll
        for (int i = 0; i < 8; ++i)
#pragma unroll
            for (int r = 0; r < 4; ++r) {
                const float c2 = fmaxf(acc[i][j][r] + cv, 0.f) * wv;
                partl[i][r] += valid ? c2 : 0.f;   // select, not *0: poison NaN safe
            }
    }
#pragma unroll
    for (int i = 0; i < 8; ++i)
#pragma unroll
        for (int r = 0; r < 4; ++r) {
            float v = partl[i][r];
#pragma unroll
            for (int off = 8; off > 0; off >>= 1) v += __shfl_xor(v, off);
            if (fr == 0) atomicAdd(&rowsum[wr * 128 + i * 16 + fg * 4 + r], v);
        }
    __syncthreads();
    if (tid < 256) part[(long)bn * MROWS + bm * 256 + tid] = rowsum[tid];
#undef IS_A
#undef IS_B
#undef MFMA_PRE
#undef MFMA_POST
}

// ---------------- broadcast: block = one s; 16 rows, nontemporal streaming stores ----------------
__global__ __launch_bounds__(256) void bcast_kernel(const float* __restrict__ part,
                                                    const float* __restrict__ b2,
                                                    float* __restrict__ out) {
    const int tid = threadIdx.x;
    const long s  = blockIdx.x;
    const float b2v = b2[0];
#pragma unroll
    for (int l = 0; l < 16; l++) {
        const long p = s * 16 + l;
        const float pv = part[p] + part[MROWS + p] + b2v;
        floatx4 v4 = {pv, pv, pv, pv};
        floatx4* dst = (floatx4*)(out + ((long)l * S_DIM + s) * S_DIM);
        __builtin_nontemporal_store(v4, dst + tid);
        __builtin_nontemporal_store(v4, dst + tid + 256);
    }
}

extern "C" void kernel_launch(void* const* d_in, const int* in_sizes, int n_in,
                              void* d_out, int out_size, void* d_ws, size_t ws_size,
                              hipStream_t stream) {
    const float* features   = (const float*)d_in[0];
    const float* in_proj_b  = (const float*)d_in[2];
    const float* out_proj_b = (const float*)d_in[4];
    const float* b1 = (const float*)d_in[6];
    const float* w2 = (const float*)d_in[7];
    const float* b2 = (const float*)d_in[8];
    float* out = (float*)d_out;

    char* p = (char*)d_ws;
    u16* fbf = (u16*)p; p += (size_t)MROWS * E_DIM * 2;        // features bf16    50.3 MB
    u16* wib = (u16*)p; p += (size_t)QKV_LD * E_DIM * 2;       // in_proj_w bf16    3.5 MB
    u16* w1b = (u16*)p; p += (size_t)384 * E_DIM * 2;          // w1 bf16           0.6 MB
    u16* WoT = (u16*)p; p += (size_t)E_DIM * E_DIM * 2;        // out_proj_w^T bf16 1.2 MB
    u16* Gbf = (u16*)p; p += (size_t)512 * E_DIM * 2;          // G = W1@Wo bf16, padded to 512 rows
    float* cbuf  = (float*)p; p += 384 * 4;
    float* partb = (float*)p; p += (size_t)2 * MROWS * 4;      // per-panel row sums 256 KB
    p = (char*)(((size_t)p + 255) & ~(size_t)255);
    u16* qkv = (u16*)p; p += (size_t)MROWS * QKV_LD * 2;       // qkv bf16 (s-major) 151 MB
    u16* ctx = qkv;                                            // attention writes over q cols

    // merged prep (3 cvts + transpose + cbias)
    prep<<<PB4, 256, 0, stream>>>(features, (const float*)d_in[1], (const float*)d_in[5],
                                  (const float*)d_in[3], out_proj_b, b1,
                                  fbf, wib, w1b, WoT, cbuf);
    // 256x256 8-phase GEMM: G = W1@Wo (6 blocks) + qkv (1152 blocks)
    qkv256<<<1158, 512, 0, stream>>>(fbf, wib, in_proj_b, qkv, w1b, WoT, Gbf);
    // attention (in place into q-columns), XCD-aligned to qkv256 writes
    attn_kernel<<<S_DIM * 2, 256, 0, stream>>>(qkv);
    // MLP 256x256 8-phase -> 2-panel partial row sums, XCD-aligned to attn writes
    mlp256<<<256, 512, 0, stream>>>(ctx, Gbf, cbuf, w2, partb);
    // broadcast write
    bcast_kernel<<<S_DIM, 256, 0, stream>>>(partb, b2, out);
}